// Round 8
// baseline (1095.453 us; speedup 1.0000x reference)
//
#include <hip/hip_runtime.h>
#include <cstdint>
#include <cstddef>

// Problem dims (fixed)
// T=10 B=4 C=256 H=W=16 N=256 HEADS=16 d=16 HID=1024 UC=40 STEP=10 R=4
#define EPSF 1e-5f

typedef __attribute__((ext_vector_type(8))) short short8;
typedef __attribute__((ext_vector_type(4))) float f32x4;

__device__ __forceinline__ unsigned short bf16_rne(float f) {
    unsigned int u = __float_as_uint(f);
    u += 0x7FFFu + ((u >> 16) & 1u);
    return (unsigned short)(u >> 16);
}
__device__ __forceinline__ float bf16f(unsigned short h) {
    return __uint_as_float(((unsigned int)h) << 16);
}

// ---------------------------------------------------------------------------
// Split fp32 W into exact bf16x3 AND pack into MFMA A-fragment order:
// P[((p*OT + ot)*KT + kt)*512 + lane*8 + j] corresponds to
// A[row = ot*16 + (lane&15)][k = kt*32 + (lane>>4)*8 + j], so a wave's
// fragment load is 64 lanes x 16B contiguous (fully coalesced).
// Threads = O*K/8.
// ---------------------------------------------------------------------------
__global__ __launch_bounds__(256) void split_pack_k(
    const float* __restrict__ W, unsigned short* __restrict__ P, int O, int K)
{
    int idx = blockIdx.x * 256 + threadIdx.x;
    int total = (O * K) >> 3;
    if (idx >= total) return;
    const int OT = O >> 4, KT = K >> 5;
    const int lane = idx & 63, tile = idx >> 6;
    const int kt = tile % KT, ot = tile / KT;
    const int quad = lane >> 4, l15 = lane & 15;
    const int row = ot * 16 + l15, col = kt * 32 + quad * 8;
    const size_t base = ((size_t)ot * KT + kt) * 512 + lane * 8;
    const size_t sOff = (size_t)OT * KT * 512;
#pragma unroll
    for (int j = 0; j < 8; ++j) {
        float v = W[(size_t)row * K + col + j];
        unsigned short h1 = bf16_rne(v);
        float r = v - bf16f(h1);
        unsigned short h2 = bf16_rne(r);
        float r2 = r - bf16f(h2);
        unsigned short h3 = bf16_rne(r2);
        P[base + j] = h1;
        P[sOff + base + j] = h2;
        P[2 * sOff + base + j] = h3;
    }
}

// ---------------------------------------------------------------------------
// MFMA GEMM v2: packed-fragment A (coalesced), double-buffered LDS B with
// register prefetch, single barrier per k-iter.
// Out[z][slice][o][n] = bn( sum_k W[z][o][k] * X[slice][k][n] + bias[o] )
// Block 256 = 4 waves, tile 64(o)x64(n), wave 32x32 = 2x2 MFMA 16x16x32.
// splitB=3: continuous B, 6 split-products (error ~2^-26 rel, << margins).
// splitB=1: binary-spike B, 3 products (exact).
// ---------------------------------------------------------------------------
struct MArgs { const unsigned short* W[3]; float* Out[3]; const float* bn[3]; };

#define MM(AP, BQ)                                                            \
    {                                                                         \
        _Pragma("unroll") for (int mt = 0; mt < 2; ++mt)                      \
        _Pragma("unroll") for (int nt = 0; nt < 2; ++nt)                      \
            acc[mt][nt] = __builtin_amdgcn_mfma_f32_16x16x32_bf16(            \
                Af[AP][mt], Bf[BQ][nt], acc[mt][nt], 0, 0, 0);                \
    }

__global__ __launch_bounds__(256, 4) void mfma_gemm2(
    MArgs a, const float* __restrict__ X, const float* __restrict__ bias,
    int O, int K, int N, int splitB)
{
    const unsigned short* __restrict__ W = a.W[blockIdx.z];
    float* __restrict__ Out = a.Out[blockIdx.z];
    const float* __restrict__ bnp = a.bn[blockIdx.z];
    const int OT = O >> 4, KT = K >> 5;
    const size_t sOff = (size_t)OT * KT * 512;

    __shared__ float Bsm[2][32][65];

    const int slice  = blockIdx.y;
    const int tilesn = N >> 6;
    const int to = (blockIdx.x / tilesn) << 6;
    const int tn = (blockIdx.x % tilesn) << 6;
    const int tid = threadIdx.x;
    const int wid = tid >> 6, lane = tid & 63;
    const int quad = lane >> 4, l15 = lane & 15;
    const int wm = (wid >> 1) << 5, wn = (wid & 1) << 5;
    const int oti0 = (to + wm) >> 4;           // A-fragment o-tile base (mt adds 1)

    f32x4 acc[2][2];
#pragma unroll
    for (int mt = 0; mt < 2; ++mt)
#pragma unroll
        for (int nt = 0; nt < 2; ++nt)
#pragma unroll
            for (int r = 0; r < 4; ++r) acc[mt][nt][r] = 0.0f;

    const float* Xs = X + (size_t)slice * K * N;
    const int nn = tid & 63, r0 = tid >> 6;    // B staging coords

    float breg[8];
    // prologue: stage B tile 0
#pragma unroll
    for (int it = 0; it < 8; ++it)
        breg[it] = Xs[(size_t)(it * 4 + r0) * N + tn + nn];
#pragma unroll
    for (int it = 0; it < 8; ++it)
        Bsm[0][it * 4 + r0][nn] = breg[it];
    __syncthreads();

    for (int kt = 0; kt < KT; ++kt) {
        const int cur = kt & 1;
        if (kt + 1 < KT) {   // global prefetch of next B tile into regs
#pragma unroll
            for (int it = 0; it < 8; ++it)
                breg[it] = Xs[(size_t)((kt + 1) * 32 + it * 4 + r0) * N + tn + nn];
        }
        // A fragment loads (coalesced 16B/lane), issued before B-split VALU
        short8 Af[3][2];
#pragma unroll
        for (int mt = 0; mt < 2; ++mt) {
            const size_t fb = ((size_t)(oti0 + mt) * KT + kt) * 512 + lane * 8;
            Af[0][mt] = *(const short8*)(W + fb);
            Af[1][mt] = *(const short8*)(W + sOff + fb);
            Af[2][mt] = *(const short8*)(W + 2 * sOff + fb);
        }
        // B fragments from LDS, split in-register
        short8 Bf[3][2];
#pragma unroll
        for (int nt = 0; nt < 2; ++nt) {
            const int bc = wn + (nt << 4) + l15;
            if (splitB == 3) {
#pragma unroll
                for (int j = 0; j < 8; ++j) {
                    float v = Bsm[cur][(quad << 3) + j][bc];
                    unsigned short h1 = bf16_rne(v);
                    float r = v - bf16f(h1);
                    unsigned short h2 = bf16_rne(r);
                    float r2 = r - bf16f(h2);
                    Bf[0][nt][j] = (short)h1;
                    Bf[1][nt][j] = (short)h2;
                    Bf[2][nt][j] = (short)bf16_rne(r2);
                }
            } else {
#pragma unroll
                for (int j = 0; j < 8; ++j)
                    Bf[0][nt][j] = (short)bf16_rne(Bsm[cur][(quad << 3) + j][bc]);
            }
        }

        if (splitB == 3) {
            MM(0, 0) MM(0, 1) MM(1, 0) MM(0, 2) MM(1, 1) MM(2, 0)
        } else {
            MM(0, 0) MM(1, 0) MM(2, 0)
        }

        if (kt + 1 < KT) {
            const int nxt = cur ^ 1;
#pragma unroll
            for (int it = 0; it < 8; ++it)
                Bsm[nxt][it * 4 + r0][nn] = breg[it];
        }
        __syncthreads();
    }

    float* Op = Out + (size_t)slice * O * N;
#pragma unroll
    for (int mt = 0; mt < 2; ++mt) {
#pragma unroll
        for (int r = 0; r < 4; ++r) {
            const int o = to + wm + (mt << 4) + (quad << 2) + r;
            float g = bnp[o], bb = bnp[O + o], m = bnp[2 * O + o], vv = bnp[3 * O + o];
            float sq = sqrtf(vv + EPSF);
            float bs = bias ? bias[o] : 0.0f;
#pragma unroll
            for (int nt = 0; nt < 2; ++nt) {
                const int n = tn + wn + (nt << 4) + l15;
                float val = acc[mt][nt][r] + bs;
                Op[(size_t)o * N + n] = (val - m) / sq * g + bb;
            }
        }
    }
}

// ---------------------------------------------------------------------------
// Weight pre-transpose for tim_up: WT[(t*27+kd*9+q)*48 + g*12 + u] =
//   up_w[(4u+g)*270 + t*27 + kd*9 + q]  (u<10; pad slots 10,11 = 0)
// ---------------------------------------------------------------------------
__global__ __launch_bounds__(256) void wt_k(
    const float* __restrict__ up_w, float* __restrict__ WT)
{
    int idx = blockIdx.x * 256 + threadIdx.x;
    if (idx >= 12960) return;
    int slot = idx % 48, tq = idx / 48;      // tq = t*27 + kd*9 + q
    int g = slot / 12, u = slot % 12;
    float v = 0.0f;
    if (u < 10) v = up_w[(4 * u + g) * 270 + tq];
    WT[idx] = v;
}

// ---------------------------------------------------------------------------
// TIM up conv3d + BN1 + inner LIF, v4: half-plane blocks, two t-phases
// (LDS 12 KB -> 8 blocks/CU; grid 2048 = 8*256 exactly, no tail).
// ---------------------------------------------------------------------------
__global__ __launch_bounds__(256, 8) void tim_up4(
    const float* __restrict__ Y, const float* __restrict__ WT,
    const float* __restrict__ bn1, float* __restrict__ SPK)
{
    __shared__ float smem[5 * 3 * 200];   // [t(5)][cc][10 rows x 20 cols]
    const int c = blockIdx.x;
    const int b = blockIdx.y >> 1, half = blockIdx.y & 1;
    const int tid = threadIdx.x;
    const int lane = tid & 63;
    const int g = __builtin_amdgcn_readfirstlane(tid >> 6);
    const int hb2 = (lane >> 4) << 1;   // 0,2,4,6
    const int wc = lane & 15;

    float acc[2][10];
#pragma unroll
    for (int i = 0; i < 2; ++i)
#pragma unroll
        for (int u = 0; u < 10; ++u) acc[i][u] = 0.0f;

#pragma unroll 1
    for (int ph = 0; ph < 2; ++ph) {
        __syncthreads();
        for (int idx = tid; idx < 3000; idx += 256) {
            int t = ph * 5 + idx / 600, rem = idx % 600;
            int cc = rem / 200, p = rem % 200;
            int rr = p / 20, col = p % 20;
            int h = half * 8 + rr - 1, ww = col - 1;
            int cs = c + cc - 1;
            float v = 0.0f;
            if (cs >= 0 && cs < 256 && h >= 0 && h < 16 && ww >= 0 && ww < 16)
                v = Y[((t * 4 + b) * 256 + cs) * 256 + h * 16 + ww];
            smem[idx] = v;
        }
        __syncthreads();

#pragma unroll 1
        for (int tt = 0; tt < 5; ++tt) {
            const int t = ph * 5 + tt;
#pragma unroll
            for (int kd = 0; kd < 3; ++kd) {
                const float* sp = &smem[tt * 600 + kd * 200 + hb2 * 20 + wc];
                float vr[4][3];
#pragma unroll
                for (int r = 0; r < 4; ++r)
#pragma unroll
                    for (int kc = 0; kc < 3; ++kc)
                        vr[r][kc] = sp[r * 20 + kc];
#pragma unroll
                for (int q = 0; q < 9; ++q) {
                    const int kh = q / 3, kw = q % 3;
                    const float4* wp =
                        (const float4*)&WT[(t * 27 + kd * 9 + q) * 48 + g * 12];
                    float4 w0 = wp[0], w1 = wp[1];
                    float4 w2 = wp[2];
                    float wr[10] = {w0.x, w0.y, w0.z, w0.w, w1.x,
                                    w1.y, w1.z, w1.w, w2.x, w2.y};
#pragma unroll
                    for (int u = 0; u < 10; ++u)
#pragma unroll
                        for (int i = 0; i < 2; ++i)
                            acc[i][u] = fmaf(wr[u], vr[i + kh][kw], acc[i][u]);
                }
            }
        }
    }

    // BN1 + inner LIF (chain over s for this wave's residue g), vth = 1.0
#pragma unroll
    for (int i = 0; i < 2; ++i) {
        const int h = half * 8 + hb2 + i;
        float mem = 0.0f;
#pragma unroll
        for (int s = 0; s < 10; ++s) {
            const int uc = 4 * s + g;
            float ga = bn1[uc], be = bn1[40 + uc], mu = bn1[80 + uc], va = bn1[120 + uc];
            float xv = (acc[i][s] - mu) / sqrtf(va + EPSF) * ga + be;
            mem += (xv - mem) * 0.5f;
            float spk = mem > 1.0f ? 1.0f : 0.0f;
            SPK[(((size_t)b * 40 + uc) * 256 + c) * 256 + h * 16 + wc] = spk;
            mem = spk > 0.0f ? 0.0f : mem;
        }
    }
}

// ---------------------------------------------------------------------------
// TIM down grouped conv3d, t-parallel: grid (c=256, b=4, t=10), block 256.
// ---------------------------------------------------------------------------
__global__ __launch_bounds__(256) void tim_down_pre(
    const float* __restrict__ SPK, const float* __restrict__ w,
    const float* __restrict__ bn2, float* __restrict__ PreY)
{
    __shared__ float smem[4 * 3 * 324];   // [r][cc][18*18]
    const int c = blockIdx.x, b = blockIdx.y, t = blockIdx.z;
    const int tid = threadIdx.x;
    for (int idx = tid; idx < 3888; idx += 256) {
        int r = idx / 972, rem = idx % 972;
        int cc = rem / 324, p = rem % 324;
        int hh = p / 18 - 1, ww = p % 18 - 1;
        int cs = c + cc - 1;
        float v = 0.0f;
        if (cs >= 0 && cs < 256 && hh >= 0 && hh < 16 && ww >= 0 && ww < 16)
            v = SPK[(((size_t)b * 40 + 4 * t + r) * 256 + cs) * 256 + hh * 16 + ww];
        smem[idx] = v;
    }
    __syncthreads();
    const int h = tid >> 4, wq = tid & 15;
    float a = 0.0f;
#pragma unroll
    for (int r = 0; r < 4; ++r)
#pragma unroll
        for (int kd = 0; kd < 3; ++kd) {
            const float* wp = w + ((t * 4 + r) * 3 + kd) * 9;
#pragma unroll
            for (int kh = 0; kh < 3; ++kh)
#pragma unroll
                for (int kw = 0; kw < 3; ++kw)
                    a = fmaf(wp[kh * 3 + kw],
                             smem[r * 972 + kd * 324 + (h + kh) * 18 + (wq + kw)], a);
        }
    a = (a - bn2[20 + t]) / sqrtf(bn2[30 + t] + EPSF) * bn2[t] + bn2[10 + t];
    PreY[((t * 4 + b) * 256 + c) * 256 + tid] = a;
}

// LIF over T (vth=1) on PreY (stride 262144), writes binary spikes to S.
__global__ __launch_bounds__(256) void lif_down(
    const float* __restrict__ PreY, float* __restrict__ S)
{
    const int idx = blockIdx.x * 256 + threadIdx.x;
    float mem = 0.0f;
    for (int t = 0; t < 10; ++t) {
        float v = PreY[t * 262144 + idx];
        mem += (v - mem) * 0.5f;
        float spk = mem > 1.0f ? 1.0f : 0.0f;
        S[t * 262144 + idx] = spk;
        mem = spk > 0.0f ? 0.0f : mem;
    }
}

// ---------------------------------------------------------------------------
// ktv[t,b,hd,j,j2] = sum_n K[..j,n] * V[..j2,n]  (exact integer dots)
// ---------------------------------------------------------------------------
__global__ __launch_bounds__(256) void ktv_k(
    const float* __restrict__ SK, const float* __restrict__ SV,
    float* __restrict__ KTV)
{
    __shared__ float ks[16 * 257], vs[16 * 257];
    const int bi = blockIdx.x;
    const int t = bi >> 6, b = (bi >> 4) & 3, hd = bi & 15;
    const int tid = threadIdx.x;
    for (int i = tid; i < 4096; i += 256) {
        int row = i >> 8, col = i & 255;
        ks[row * 257 + col] = SK[((t * 4 + b) * 256 + hd * 16 + row) * 256 + col];
        vs[row * 257 + col] = SV[((t * 4 + b) * 256 + hd * 16 + row) * 256 + col];
    }
    __syncthreads();
    const int j = tid >> 4, j2 = tid & 15;
    float a0 = 0.0f, a1 = 0.0f, a2 = 0.0f, a3 = 0.0f;
#pragma unroll 4
    for (int n = 0; n < 256; n += 4) {
        a0 = fmaf(ks[j * 257 + n + 0], vs[j2 * 257 + n + 0], a0);
        a1 = fmaf(ks[j * 257 + n + 1], vs[j2 * 257 + n + 1], a1);
        a2 = fmaf(ks[j * 257 + n + 2], vs[j2 * 257 + n + 2], a2);
        a3 = fmaf(ks[j * 257 + n + 3], vs[j2 * 257 + n + 3], a3);
    }
    KTV[((t * 4 + b) * 16 + hd) * 256 + tid] = (a0 + a1) + (a2 + a3);
}

// ---------------------------------------------------------------------------
// o = q @ ktv * 0.25 (exact) fused with attn_lif (vth=0.5) -> spikes (t,b,c,n)
// ---------------------------------------------------------------------------
__global__ __launch_bounds__(256) void attn_k(
    const float* __restrict__ SQ, const float* __restrict__ KTV,
    float* __restrict__ OSPK)
{
    __shared__ float kt[2560];    // [t][j*16+j2]
    __shared__ float qs[16 * 17]; // [nl][j], padded
    const int x = blockIdx.x;
    const int b = x >> 8, hd = (x >> 4) & 15, ng = x & 15;
    const int tid = threadIdx.x;
    const int j2 = tid >> 4, nl = tid & 15;
    const int n = ng * 16 + nl;
    for (int i = tid; i < 2560; i += 256) {
        int t = i >> 8;
        kt[i] = KTV[((t * 4 + b) * 16 + hd) * 256 + (i & 255)];
    }
    float mem = 0.0f;
    for (int t = 0; t < 10; ++t) {
        __syncthreads();
        qs[nl * 17 + j2] = SQ[((t * 4 + b) * 256 + hd * 16 + j2) * 256 + n];
        __syncthreads();
        float a = 0.0f;
#pragma unroll
        for (int j = 0; j < 16; ++j)
            a = fmaf(qs[nl * 17 + j], kt[t * 256 + j * 16 + j2], a);
        a *= 0.25f;
        mem += (a - mem) * 0.5f;
        float spk = mem > 0.5f ? 1.0f : 0.0f;
        OSPK[((t * 4 + b) * 256 + hd * 16 + j2) * 256 + n] = spk;
        mem = spk > 0.0f ? 0.0f : mem;
    }
}

// LIF over T (vth=1) on P, then H = x + spikes. Per-t slice 262,144.
__global__ __launch_bounds__(256) void ssa_lif_res(
    const float* __restrict__ P, const float* __restrict__ x,
    float* __restrict__ H)
{
    const int idx = blockIdx.x * 256 + threadIdx.x;
    float mem = 0.0f;
    for (int t = 0; t < 10; ++t) {
        float v = P[t * 262144 + idx];
        mem += (v - mem) * 0.5f;
        float spk = mem > 1.0f ? 1.0f : 0.0f;
        H[t * 262144 + idx] = x[t * 262144 + idx] + spk;
        mem = spk > 0.0f ? 0.0f : mem;
    }
}

// In-place LIF over T (vth=1), per-t slice 1,048,576 (fc1 activations).
__global__ __launch_bounds__(256) void lif_ip(float* __restrict__ A)
{
    const int idx = blockIdx.x * 256 + threadIdx.x;
    float mem = 0.0f;
    for (int t = 0; t < 10; ++t) {
        float v = A[t * 1048576 + idx];
        mem += (v - mem) * 0.5f;
        float spk = mem > 1.0f ? 1.0f : 0.0f;
        A[t * 1048576 + idx] = spk;
        mem = spk > 0.0f ? 0.0f : mem;
    }
}

// out = H + lif(P) over T (vth=1). Per-t slice 262,144.
__global__ __launch_bounds__(256) void final_k(
    const float* __restrict__ P, const float* __restrict__ H,
    float* __restrict__ out)
{
    const int idx = blockIdx.x * 256 + threadIdx.x;
    float mem = 0.0f;
    for (int t = 0; t < 10; ++t) {
        float v = P[t * 262144 + idx];
        mem += (v - mem) * 0.5f;
        float spk = mem > 1.0f ? 1.0f : 0.0f;
        out[t * 262144 + idx] = H[t * 262144 + idx] + spk;
        mem = spk > 0.0f ? 0.0f : mem;
    }
}

// ---------------------------------------------------------------------------
extern "C" void kernel_launch(void* const* d_in, const int* in_sizes, int n_in,
                              void* d_out, int out_size, void* d_ws, size_t ws_size,
                              hipStream_t stream)
{
    const float* x        = (const float*)d_in[0];
    const float* q_w      = (const float*)d_in[1];
    const float* q_bn     = (const float*)d_in[2];
    const float* k_w      = (const float*)d_in[3];
    const float* k_bn     = (const float*)d_in[4];
    const float* v_w      = (const float*)d_in[5];
    const float* v_bn     = (const float*)d_in[6];
    const float* proj_w   = (const float*)d_in[7];
    const float* proj_bn  = (const float*)d_in[8];
    const float* up_w     = (const float*)d_in[9];
    const float* bn1      = (const float*)d_in[10];
    const float* down_w   = (const float*)d_in[11];
    const float* bn2      = (const float*)d_in[12];
    const float* fc1_w    = (const float*)d_in[13];
    const float* fc1_b    = (const float*)d_in[14];
    const float* fc1_bn   = (const float*)d_in[15];
    const float* fc2_w    = (const float*)d_in[16];
    const float* fc2_b    = (const float*)d_in[17];
    const float* fc2_bn   = (const float*)d_in[18];

    float* ws   = (float*)d_ws;
    float* Y    = ws;                    // 2,621,440  (qkv Y0 / down pre-LIF / attn spikes / fc W-packs)
    float* ASPK = Y + 2621440;           // 10,485,760 (qkv+proj W-packs / up spikes / fc1 out+spikes)
    float* SQ   = ASPK + 10485760;       // 2,621,440  (q spikes / proj out)
    float* SK   = SQ + 2621440;          // 2,621,440  (qkv Y1 / k spikes / fc2 out)
    float* SV   = SK + 2621440;          // 2,621,440  (qkv Y2 / v spikes / H)
    float* KTV  = SV + 2621440;          // 163,840  (WT during tim phase, then ktv)
    float* WT   = KTV;                   // 12,960 <= 163,840; dead before ktv_k runs
    // total ws: 21,135,360 floats = 84.5 MB (W-packs alias dead regions)

    float* Yb[3] = {Y, SK, SV};          // branch BN outputs
    float* Sb[3] = {SQ, SK, SV};         // branch spike outputs

    // packed bf16x3 W for q/k/v live in ASPK (dead until first tim_up4)
    unsigned short* qs_s = (unsigned short*)ASPK;      // 196,608 halves each
    unsigned short* ks_s = qs_s + 196608;
    unsigned short* vs_s = qs_s + 393216;

    wt_k<<<51, 256, 0, stream>>>(up_w, WT);
    split_pack_k<<<32, 256, 0, stream>>>(q_w, qs_s, 256, 256);
    split_pack_k<<<32, 256, 0, stream>>>(k_w, ks_s, 256, 256);
    split_pack_k<<<32, 256, 0, stream>>>(v_w, vs_s, 256, 256);

    MArgs qkv;
    qkv.W[0] = qs_s;  qkv.W[1] = ks_s;  qkv.W[2] = vs_s;
    qkv.Out[0] = Yb[0]; qkv.Out[1] = Yb[1]; qkv.Out[2] = Yb[2];
    qkv.bn[0] = q_bn; qkv.bn[1] = k_bn; qkv.bn[2] = v_bn;
    mfma_gemm2<<<dim3(16, 40, 3), 256, 0, stream>>>(qkv, x, nullptr, 256, 256, 256, 3);

    for (int br = 0; br < 3; ++br) {
        tim_up4<<<dim3(256, 8), 256, 0, stream>>>(Yb[br], WT, bn1, ASPK);
        tim_down_pre<<<dim3(256, 4, 10), 256, 0, stream>>>(ASPK, down_w, bn2, Y);
        lif_down<<<1024, 256, 0, stream>>>(Y, Sb[br]);
    }

    ktv_k<<<640, 256, 0, stream>>>(SK, SV, KTV);
    attn_k<<<1024, 256, 0, stream>>>(SQ, KTV, Y);               // Y <- attn spikes

    // proj: binary B (attn spikes) -> splitB=1; W-pack in ASPK (dead now)
    unsigned short* pj_s = (unsigned short*)ASPK;
    split_pack_k<<<32, 256, 0, stream>>>(proj_w, pj_s, 256, 256);
    MArgs gp; gp.W[0] = gp.W[1] = gp.W[2] = pj_s;
    gp.Out[0] = gp.Out[1] = gp.Out[2] = SQ;
    gp.bn[0] = gp.bn[1] = gp.bn[2] = proj_bn;
    mfma_gemm2<<<dim3(16, 40, 1), 256, 0, stream>>>(gp, Y, nullptr, 256, 256, 256, 1);
    ssa_lif_res<<<1024, 256, 0, stream>>>(SQ, x, SV);           // SV <- H

    // fc1: continuous B (H) -> splitB=3; W-pack in Y (attn spikes dead now)
    unsigned short* f1_s = (unsigned short*)Y;
    split_pack_k<<<128, 256, 0, stream>>>(fc1_w, f1_s, 1024, 256);
    MArgs g1; g1.W[0] = g1.W[1] = g1.W[2] = f1_s;
    g1.Out[0] = g1.Out[1] = g1.Out[2] = ASPK;
    g1.bn[0] = g1.bn[1] = g1.bn[2] = fc1_bn;
    mfma_gemm2<<<dim3(64, 40, 1), 256, 0, stream>>>(g1, SV, fc1_b, 1024, 256, 256, 3);
    lif_ip<<<4096, 256, 0, stream>>>(ASPK);

    // fc2: binary B (fc1 spikes) -> splitB=1; W-pack reuses Y
    unsigned short* f2_s = (unsigned short*)Y;
    split_pack_k<<<128, 256, 0, stream>>>(fc2_w, f2_s, 256, 1024);
    MArgs g2; g2.W[0] = g2.W[1] = g2.W[2] = f2_s;
    g2.Out[0] = g2.Out[1] = g2.Out[2] = SK;
    g2.bn[0] = g2.bn[1] = g2.bn[2] = fc2_bn;
    mfma_gemm2<<<dim3(16, 40, 1), 256, 0, stream>>>(g2, ASPK, fc2_b, 256, 1024, 256, 1);
    final_k<<<1024, 256, 0, stream>>>(SK, SV, (float*)d_out);
}

// Round 9
// 780.908 us; speedup vs baseline: 1.4028x; 1.4028x over previous
//
#include <hip/hip_runtime.h>
#include <cstdint>
#include <cstddef>

// Problem dims (fixed)
// T=10 B=4 C=256 H=W=16 N=256 HEADS=16 d=16 HID=1024 UC=40 STEP=10 R=4
#define EPSF 1e-5f

typedef __attribute__((ext_vector_type(8))) short short8;
typedef __attribute__((ext_vector_type(4))) float f32x4;

__device__ __forceinline__ unsigned short bf16_rne(float f) {
    unsigned int u = __float_as_uint(f);
    u += 0x7FFFu + ((u >> 16) & 1u);
    return (unsigned short)(u >> 16);
}
__device__ __forceinline__ float bf16f(unsigned short h) {
    return __uint_as_float(((unsigned int)h) << 16);
}

// ---------------------------------------------------------------------------
// Split fp32 W into exact bf16x3 AND pack into MFMA A-fragment order:
// P[((p*OT + ot)*KT + kt)*512 + lane*8 + j] corresponds to
// A[row = ot*16 + (lane&15)][k = kt*32 + (lane>>4)*8 + j], so a wave's
// fragment load is 64 lanes x 16B contiguous (fully coalesced).
// ---------------------------------------------------------------------------
__global__ __launch_bounds__(256) void split_pack_k(
    const float* __restrict__ W, unsigned short* __restrict__ P, int O, int K)
{
    int idx = blockIdx.x * 256 + threadIdx.x;
    int total = (O * K) >> 3;
    if (idx >= total) return;
    const int OT = O >> 4, KT = K >> 5;
    const int lane = idx & 63, tile = idx >> 6;
    const int kt = tile % KT, ot = tile / KT;
    const int quad = lane >> 4, l15 = lane & 15;
    const int row = ot * 16 + l15, col = kt * 32 + quad * 8;
    const size_t base = ((size_t)ot * KT + kt) * 512 + lane * 8;
    const size_t sOff = (size_t)OT * KT * 512;
#pragma unroll
    for (int j = 0; j < 8; ++j) {
        float v = W[(size_t)row * K + col + j];
        unsigned short h1 = bf16_rne(v);
        float r = v - bf16f(h1);
        unsigned short h2 = bf16_rne(r);
        float r2 = r - bf16f(h2);
        unsigned short h3 = bf16_rne(r2);
        P[base + j] = h1;
        P[sOff + base + j] = h2;
        P[2 * sOff + base + j] = h3;
    }
}

// ---------------------------------------------------------------------------
// MFMA GEMM v2.1: packed-fragment A (coalesced), double-buffered LDS B with
// register prefetch, single barrier per k-iter.
// __launch_bounds__(256, 2): ~110 live VGPRs must NOT spill (round-8 used
// (256,4) and spilled ~60 B/thread/iter -> 320 MB scratch writes).
// splitB=3: continuous B, 6 split-products. splitB=1: binary B, exact.
// ---------------------------------------------------------------------------
struct MArgs { const unsigned short* W[3]; float* Out[3]; const float* bn[3]; };

#define MM(AP, BQ)                                                            \
    {                                                                         \
        _Pragma("unroll") for (int mt = 0; mt < 2; ++mt)                      \
        _Pragma("unroll") for (int nt = 0; nt < 2; ++nt)                      \
            acc[mt][nt] = __builtin_amdgcn_mfma_f32_16x16x32_bf16(            \
                Af[AP][mt], Bf[BQ][nt], acc[mt][nt], 0, 0, 0);                \
    }

__global__ __launch_bounds__(256, 2) void mfma_gemm2(
    MArgs a, const float* __restrict__ X, const float* __restrict__ bias,
    int O, int K, int N, int splitB)
{
    const unsigned short* __restrict__ W = a.W[blockIdx.z];
    float* __restrict__ Out = a.Out[blockIdx.z];
    const float* __restrict__ bnp = a.bn[blockIdx.z];
    const int OT = O >> 4, KT = K >> 5;
    const size_t sOff = (size_t)OT * KT * 512;

    __shared__ float Bsm[2][32][65];

    const int slice  = blockIdx.y;
    const int tilesn = N >> 6;
    const int to = (blockIdx.x / tilesn) << 6;
    const int tn = (blockIdx.x % tilesn) << 6;
    const int tid = threadIdx.x;
    const int wid = tid >> 6, lane = tid & 63;
    const int quad = lane >> 4, l15 = lane & 15;
    const int wm = (wid >> 1) << 5, wn = (wid & 1) << 5;
    const int oti0 = (to + wm) >> 4;           // A-fragment o-tile base (mt adds 1)

    f32x4 acc[2][2];
#pragma unroll
    for (int mt = 0; mt < 2; ++mt)
#pragma unroll
        for (int nt = 0; nt < 2; ++nt)
#pragma unroll
            for (int r = 0; r < 4; ++r) acc[mt][nt][r] = 0.0f;

    const float* Xs = X + (size_t)slice * K * N;
    const int nn = tid & 63, r0 = tid >> 6;    // B staging coords

    float breg[8];
    // prologue: stage B tile 0
#pragma unroll
    for (int it = 0; it < 8; ++it)
        breg[it] = Xs[(size_t)(it * 4 + r0) * N + tn + nn];
#pragma unroll
    for (int it = 0; it < 8; ++it)
        Bsm[0][it * 4 + r0][nn] = breg[it];
    __syncthreads();

    for (int kt = 0; kt < KT; ++kt) {
        const int cur = kt & 1;
        if (kt + 1 < KT) {   // global prefetch of next B tile into regs
#pragma unroll
            for (int it = 0; it < 8; ++it)
                breg[it] = Xs[(size_t)((kt + 1) * 32 + it * 4 + r0) * N + tn + nn];
        }
        // A fragment loads (coalesced 16B/lane)
        short8 Af[3][2];
#pragma unroll
        for (int mt = 0; mt < 2; ++mt) {
            const size_t fb = ((size_t)(oti0 + mt) * KT + kt) * 512 + lane * 8;
            Af[0][mt] = *(const short8*)(W + fb);
            Af[1][mt] = *(const short8*)(W + sOff + fb);
            Af[2][mt] = *(const short8*)(W + 2 * sOff + fb);
        }
        // B fragments from LDS, split in-register
        short8 Bf[3][2];
#pragma unroll
        for (int nt = 0; nt < 2; ++nt) {
            const int bc = wn + (nt << 4) + l15;
            if (splitB == 3) {
#pragma unroll
                for (int j = 0; j < 8; ++j) {
                    float v = Bsm[cur][(quad << 3) + j][bc];
                    unsigned short h1 = bf16_rne(v);
                    float r = v - bf16f(h1);
                    unsigned short h2 = bf16_rne(r);
                    float r2 = r - bf16f(h2);
                    Bf[0][nt][j] = (short)h1;
                    Bf[1][nt][j] = (short)h2;
                    Bf[2][nt][j] = (short)bf16_rne(r2);
                }
            } else {
#pragma unroll
                for (int j = 0; j < 8; ++j)
                    Bf[0][nt][j] = (short)bf16_rne(Bsm[cur][(quad << 3) + j][bc]);
            }
        }

        if (splitB == 3) {
            MM(0, 0) MM(0, 1) MM(1, 0) MM(0, 2) MM(1, 1) MM(2, 0)
        } else {
            MM(0, 0) MM(1, 0) MM(2, 0)
        }

        if (kt + 1 < KT) {
            const int nxt = cur ^ 1;
#pragma unroll
            for (int it = 0; it < 8; ++it)
                Bsm[nxt][it * 4 + r0][nn] = breg[it];
        }
        __syncthreads();
    }

    float* Op = Out + (size_t)slice * O * N;
#pragma unroll
    for (int mt = 0; mt < 2; ++mt) {
#pragma unroll
        for (int r = 0; r < 4; ++r) {
            const int o = to + wm + (mt << 4) + (quad << 2) + r;
            float g = bnp[o], bb = bnp[O + o], m = bnp[2 * O + o], vv = bnp[3 * O + o];
            float sq = sqrtf(vv + EPSF);
            float bs = bias ? bias[o] : 0.0f;
#pragma unroll
            for (int nt = 0; nt < 2; ++nt) {
                const int n = tn + wn + (nt << 4) + l15;
                float val = acc[mt][nt][r] + bs;
                Op[(size_t)o * N + n] = (val - m) / sq * g + bb;
            }
        }
    }
}

// ---------------------------------------------------------------------------
// Weight pre-transpose for tim_up: WT[(t*27+kd*9+q)*48 + g*12 + u] =
//   up_w[(4u+g)*270 + t*27 + kd*9 + q]  (u<10; pad slots 10,11 = 0)
// ---------------------------------------------------------------------------
__global__ __launch_bounds__(256) void wt_k(
    const float* __restrict__ up_w, float* __restrict__ WT)
{
    int idx = blockIdx.x * 256 + threadIdx.x;
    if (idx >= 12960) return;
    int slot = idx % 48, tq = idx / 48;      // tq = t*27 + kd*9 + q
    int g = slot / 12, u = slot % 12;
    float v = 0.0f;
    if (u < 10) v = up_w[(4 * u + g) * 270 + tq];
    WT[idx] = v;
}

// ---------------------------------------------------------------------------
// TIM up conv3d + BN1 + inner LIF, v4: half-plane blocks, two t-phases
// (LDS 12 KB -> 8 blocks/CU; grid 2048 = 8*256 exactly, no tail).
// ---------------------------------------------------------------------------
__global__ __launch_bounds__(256, 8) void tim_up4(
    const float* __restrict__ Y, const float* __restrict__ WT,
    const float* __restrict__ bn1, float* __restrict__ SPK)
{
    __shared__ float smem[5 * 3 * 200];   // [t(5)][cc][10 rows x 20 cols]
    const int c = blockIdx.x;
    const int b = blockIdx.y >> 1, half = blockIdx.y & 1;
    const int tid = threadIdx.x;
    const int lane = tid & 63;
    const int g = __builtin_amdgcn_readfirstlane(tid >> 6);
    const int hb2 = (lane >> 4) << 1;   // 0,2,4,6
    const int wc = lane & 15;

    float acc[2][10];
#pragma unroll
    for (int i = 0; i < 2; ++i)
#pragma unroll
        for (int u = 0; u < 10; ++u) acc[i][u] = 0.0f;

#pragma unroll 1
    for (int ph = 0; ph < 2; ++ph) {
        __syncthreads();
        for (int idx = tid; idx < 3000; idx += 256) {
            int t = ph * 5 + idx / 600, rem = idx % 600;
            int cc = rem / 200, p = rem % 200;
            int rr = p / 20, col = p % 20;
            int h = half * 8 + rr - 1, ww = col - 1;
            int cs = c + cc - 1;
            float v = 0.0f;
            if (cs >= 0 && cs < 256 && h >= 0 && h < 16 && ww >= 0 && ww < 16)
                v = Y[((t * 4 + b) * 256 + cs) * 256 + h * 16 + ww];
            smem[idx] = v;
        }
        __syncthreads();

#pragma unroll 1
        for (int tt = 0; tt < 5; ++tt) {
            const int t = ph * 5 + tt;
#pragma unroll
            for (int kd = 0; kd < 3; ++kd) {
                const float* sp = &smem[tt * 600 + kd * 200 + hb2 * 20 + wc];
                float vr[4][3];
#pragma unroll
                for (int r = 0; r < 4; ++r)
#pragma unroll
                    for (int kc = 0; kc < 3; ++kc)
                        vr[r][kc] = sp[r * 20 + kc];
#pragma unroll
                for (int q = 0; q < 9; ++q) {
                    const int kh = q / 3, kw = q % 3;
                    const float4* wp =
                        (const float4*)&WT[(t * 27 + kd * 9 + q) * 48 + g * 12];
                    float4 w0 = wp[0], w1 = wp[1];
                    float4 w2 = wp[2];
                    float wr[10] = {w0.x, w0.y, w0.z, w0.w, w1.x,
                                    w1.y, w1.z, w1.w, w2.x, w2.y};
#pragma unroll
                    for (int u = 0; u < 10; ++u)
#pragma unroll
                        for (int i = 0; i < 2; ++i)
                            acc[i][u] = fmaf(wr[u], vr[i + kh][kw], acc[i][u]);
                }
            }
        }
    }

    // BN1 + inner LIF (chain over s for this wave's residue g), vth = 1.0
#pragma unroll
    for (int i = 0; i < 2; ++i) {
        const int h = half * 8 + hb2 + i;
        float mem = 0.0f;
#pragma unroll
        for (int s = 0; s < 10; ++s) {
            const int uc = 4 * s + g;
            float ga = bn1[uc], be = bn1[40 + uc], mu = bn1[80 + uc], va = bn1[120 + uc];
            float xv = (acc[i][s] - mu) / sqrtf(va + EPSF) * ga + be;
            mem += (xv - mem) * 0.5f;
            float spk = mem > 1.0f ? 1.0f : 0.0f;
            SPK[(((size_t)b * 40 + uc) * 256 + c) * 256 + h * 16 + wc] = spk;
            mem = spk > 0.0f ? 0.0f : mem;
        }
    }
}

// ---------------------------------------------------------------------------
// TIM down grouped conv3d, t-parallel: grid (c=256, b=4, t=10), block 256.
// ---------------------------------------------------------------------------
__global__ __launch_bounds__(256) void tim_down_pre(
    const float* __restrict__ SPK, const float* __restrict__ w,
    const float* __restrict__ bn2, float* __restrict__ PreY)
{
    __shared__ float smem[4 * 3 * 324];   // [r][cc][18*18]
    const int c = blockIdx.x, b = blockIdx.y, t = blockIdx.z;
    const int tid = threadIdx.x;
    for (int idx = tid; idx < 3888; idx += 256) {
        int r = idx / 972, rem = idx % 972;
        int cc = rem / 324, p = rem % 324;
        int hh = p / 18 - 1, ww = p % 18 - 1;
        int cs = c + cc - 1;
        float v = 0.0f;
        if (cs >= 0 && cs < 256 && hh >= 0 && hh < 16 && ww >= 0 && ww < 16)
            v = SPK[(((size_t)b * 40 + 4 * t + r) * 256 + cs) * 256 + hh * 16 + ww];
        smem[idx] = v;
    }
    __syncthreads();
    const int h = tid >> 4, wq = tid & 15;
    float a = 0.0f;
#pragma unroll
    for (int r = 0; r < 4; ++r)
#pragma unroll
        for (int kd = 0; kd < 3; ++kd) {
            const float* wp = w + ((t * 4 + r) * 3 + kd) * 9;
#pragma unroll
            for (int kh = 0; kh < 3; ++kh)
#pragma unroll
                for (int kw = 0; kw < 3; ++kw)
                    a = fmaf(wp[kh * 3 + kw],
                             smem[r * 972 + kd * 324 + (h + kh) * 18 + (wq + kw)], a);
        }
    a = (a - bn2[20 + t]) / sqrtf(bn2[30 + t] + EPSF) * bn2[t] + bn2[10 + t];
    PreY[((t * 4 + b) * 256 + c) * 256 + tid] = a;
}

// LIF over T (vth=1) on PreY (stride 262144), writes binary spikes to S.
__global__ __launch_bounds__(256) void lif_down(
    const float* __restrict__ PreY, float* __restrict__ S)
{
    const int idx = blockIdx.x * 256 + threadIdx.x;
    float mem = 0.0f;
    for (int t = 0; t < 10; ++t) {
        float v = PreY[t * 262144 + idx];
        mem += (v - mem) * 0.5f;
        float spk = mem > 1.0f ? 1.0f : 0.0f;
        S[t * 262144 + idx] = spk;
        mem = spk > 0.0f ? 0.0f : mem;
    }
}

// ---------------------------------------------------------------------------
// ktv[t,b,hd,j,j2] = sum_n K[..j,n] * V[..j2,n]  (exact integer dots)
// ---------------------------------------------------------------------------
__global__ __launch_bounds__(256) void ktv_k(
    const float* __restrict__ SK, const float* __restrict__ SV,
    float* __restrict__ KTV)
{
    __shared__ float ks[16 * 257], vs[16 * 257];
    const int bi = blockIdx.x;
    const int t = bi >> 6, b = (bi >> 4) & 3, hd = bi & 15;
    const int tid = threadIdx.x;
    for (int i = tid; i < 4096; i += 256) {
        int row = i >> 8, col = i & 255;
        ks[row * 257 + col] = SK[((t * 4 + b) * 256 + hd * 16 + row) * 256 + col];
        vs[row * 257 + col] = SV[((t * 4 + b) * 256 + hd * 16 + row) * 256 + col];
    }
    __syncthreads();
    const int j = tid >> 4, j2 = tid & 15;
    float a0 = 0.0f, a1 = 0.0f, a2 = 0.0f, a3 = 0.0f;
#pragma unroll 4
    for (int n = 0; n < 256; n += 4) {
        a0 = fmaf(ks[j * 257 + n + 0], vs[j2 * 257 + n + 0], a0);
        a1 = fmaf(ks[j * 257 + n + 1], vs[j2 * 257 + n + 1], a1);
        a2 = fmaf(ks[j * 257 + n + 2], vs[j2 * 257 + n + 2], a2);
        a3 = fmaf(ks[j * 257 + n + 3], vs[j2 * 257 + n + 3], a3);
    }
    KTV[((t * 4 + b) * 16 + hd) * 256 + tid] = (a0 + a1) + (a2 + a3);
}

// ---------------------------------------------------------------------------
// o = q @ ktv * 0.25 (exact) fused with attn_lif (vth=0.5) -> spikes (t,b,c,n)
// ---------------------------------------------------------------------------
__global__ __launch_bounds__(256) void attn_k(
    const float* __restrict__ SQ, const float* __restrict__ KTV,
    float* __restrict__ OSPK)
{
    __shared__ float kt[2560];    // [t][j*16+j2]
    __shared__ float qs[16 * 17]; // [nl][j], padded
    const int x = blockIdx.x;
    const int b = x >> 8, hd = (x >> 4) & 15, ng = x & 15;
    const int tid = threadIdx.x;
    const int j2 = tid >> 4, nl = tid & 15;
    const int n = ng * 16 + nl;
    for (int i = tid; i < 2560; i += 256) {
        int t = i >> 8;
        kt[i] = KTV[((t * 4 + b) * 16 + hd) * 256 + (i & 255)];
    }
    float mem = 0.0f;
    for (int t = 0; t < 10; ++t) {
        __syncthreads();
        qs[nl * 17 + j2] = SQ[((t * 4 + b) * 256 + hd * 16 + j2) * 256 + n];
        __syncthreads();
        float a = 0.0f;
#pragma unroll
        for (int j = 0; j < 16; ++j)
            a = fmaf(qs[nl * 17 + j], kt[t * 256 + j * 16 + j2], a);
        a *= 0.25f;
        mem += (a - mem) * 0.5f;
        float spk = mem > 0.5f ? 1.0f : 0.0f;
        OSPK[((t * 4 + b) * 256 + hd * 16 + j2) * 256 + n] = spk;
        mem = spk > 0.0f ? 0.0f : mem;
    }
}

// LIF over T (vth=1) on P, then H = x + spikes. Per-t slice 262,144.
__global__ __launch_bounds__(256) void ssa_lif_res(
    const float* __restrict__ P, const float* __restrict__ x,
    float* __restrict__ H)
{
    const int idx = blockIdx.x * 256 + threadIdx.x;
    float mem = 0.0f;
    for (int t = 0; t < 10; ++t) {
        float v = P[t * 262144 + idx];
        mem += (v - mem) * 0.5f;
        float spk = mem > 1.0f ? 1.0f : 0.0f;
        H[t * 262144 + idx] = x[t * 262144 + idx] + spk;
        mem = spk > 0.0f ? 0.0f : mem;
    }
}

// In-place LIF over T (vth=1), per-t slice 1,048,576 (fc1 activations).
__global__ __launch_bounds__(256) void lif_ip(float* __restrict__ A)
{
    const int idx = blockIdx.x * 256 + threadIdx.x;
    float mem = 0.0f;
    for (int t = 0; t < 10; ++t) {
        float v = A[t * 1048576 + idx];
        mem += (v - mem) * 0.5f;
        float spk = mem > 1.0f ? 1.0f : 0.0f;
        A[t * 1048576 + idx] = spk;
        mem = spk > 0.0f ? 0.0f : mem;
    }
}

// out = H + lif(P) over T (vth=1). Per-t slice 262,144.
__global__ __launch_bounds__(256) void final_k(
    const float* __restrict__ P, const float* __restrict__ H,
    float* __restrict__ out)
{
    const int idx = blockIdx.x * 256 + threadIdx.x;
    float mem = 0.0f;
    for (int t = 0; t < 10; ++t) {
        float v = P[t * 262144 + idx];
        mem += (v - mem) * 0.5f;
        float spk = mem > 1.0f ? 1.0f : 0.0f;
        out[t * 262144 + idx] = H[t * 262144 + idx] + spk;
        mem = spk > 0.0f ? 0.0f : mem;
    }
}

// ---------------------------------------------------------------------------
extern "C" void kernel_launch(void* const* d_in, const int* in_sizes, int n_in,
                              void* d_out, int out_size, void* d_ws, size_t ws_size,
                              hipStream_t stream)
{
    const float* x        = (const float*)d_in[0];
    const float* q_w      = (const float*)d_in[1];
    const float* q_bn     = (const float*)d_in[2];
    const float* k_w      = (const float*)d_in[3];
    const float* k_bn     = (const float*)d_in[4];
    const float* v_w      = (const float*)d_in[5];
    const float* v_bn     = (const float*)d_in[6];
    const float* proj_w   = (const float*)d_in[7];
    const float* proj_bn  = (const float*)d_in[8];
    const float* up_w     = (const float*)d_in[9];
    const float* bn1      = (const float*)d_in[10];
    const float* down_w   = (const float*)d_in[11];
    const float* bn2      = (const float*)d_in[12];
    const float* fc1_w    = (const float*)d_in[13];
    const float* fc1_b    = (const float*)d_in[14];
    const float* fc1_bn   = (const float*)d_in[15];
    const float* fc2_w    = (const float*)d_in[16];
    const float* fc2_b    = (const float*)d_in[17];
    const float* fc2_bn   = (const float*)d_in[18];

    float* ws   = (float*)d_ws;
    float* Y    = ws;                    // 2,621,440  (qkv Y0 / down pre-LIF / attn spikes / fc W-packs)
    float* ASPK = Y + 2621440;           // 10,485,760 (qkv+proj W-packs / up spikes / fc1 out+spikes)
    float* SQ   = ASPK + 10485760;       // 2,621,440  (q spikes / proj out)
    float* SK   = SQ + 2621440;          // 2,621,440  (qkv Y1 / k spikes / fc2 out)
    float* SV   = SK + 2621440;          // 2,621,440  (qkv Y2 / v spikes / H)
    float* KTV  = SV + 2621440;          // 163,840  (WT during tim phase, then ktv)
    float* WT   = KTV;                   // 12,960 <= 163,840; dead before ktv_k runs
    // total ws: 21,135,360 floats = 84.5 MB (W-packs alias dead regions)

    float* Yb[3] = {Y, SK, SV};          // branch BN outputs
    float* Sb[3] = {SQ, SK, SV};         // branch spike outputs

    // packed bf16x3 W for q/k/v live in ASPK (dead until first tim_up4)
    unsigned short* qs_s = (unsigned short*)ASPK;      // 196,608 halves each
    unsigned short* ks_s = qs_s + 196608;
    unsigned short* vs_s = qs_s + 393216;

    wt_k<<<51, 256, 0, stream>>>(up_w, WT);
    split_pack_k<<<32, 256, 0, stream>>>(q_w, qs_s, 256, 256);
    split_pack_k<<<32, 256, 0, stream>>>(k_w, ks_s, 256, 256);
    split_pack_k<<<32, 256, 0, stream>>>(v_w, vs_s, 256, 256);

    MArgs qkv;
    qkv.W[0] = qs_s;  qkv.W[1] = ks_s;  qkv.W[2] = vs_s;
    qkv.Out[0] = Yb[0]; qkv.Out[1] = Yb[1]; qkv.Out[2] = Yb[2];
    qkv.bn[0] = q_bn; qkv.bn[1] = k_bn; qkv.bn[2] = v_bn;
    mfma_gemm2<<<dim3(16, 40, 3), 256, 0, stream>>>(qkv, x, nullptr, 256, 256, 256, 3);

    for (int br = 0; br < 3; ++br) {
        tim_up4<<<dim3(256, 8), 256, 0, stream>>>(Yb[br], WT, bn1, ASPK);
        tim_down_pre<<<dim3(256, 4, 10), 256, 0, stream>>>(ASPK, down_w, bn2, Y);
        lif_down<<<1024, 256, 0, stream>>>(Y, Sb[br]);
    }

    ktv_k<<<640, 256, 0, stream>>>(SK, SV, KTV);
    attn_k<<<1024, 256, 0, stream>>>(SQ, KTV, Y);               // Y <- attn spikes

    // proj: binary B (attn spikes) -> splitB=1; W-pack in ASPK (dead now)
    unsigned short* pj_s = (unsigned short*)ASPK;
    split_pack_k<<<32, 256, 0, stream>>>(proj_w, pj_s, 256, 256);
    MArgs gp; gp.W[0] = gp.W[1] = gp.W[2] = pj_s;
    gp.Out[0] = gp.Out[1] = gp.Out[2] = SQ;
    gp.bn[0] = gp.bn[1] = gp.bn[2] = proj_bn;
    mfma_gemm2<<<dim3(16, 40, 1), 256, 0, stream>>>(gp, Y, nullptr, 256, 256, 256, 1);
    ssa_lif_res<<<1024, 256, 0, stream>>>(SQ, x, SV);           // SV <- H

    // fc1: continuous B (H) -> splitB=3; W-pack in Y (attn spikes dead now)
    unsigned short* f1_s = (unsigned short*)Y;
    split_pack_k<<<128, 256, 0, stream>>>(fc1_w, f1_s, 1024, 256);
    MArgs g1; g1.W[0] = g1.W[1] = g1.W[2] = f1_s;
    g1.Out[0] = g1.Out[1] = g1.Out[2] = ASPK;
    g1.bn[0] = g1.bn[1] = g1.bn[2] = fc1_bn;
    mfma_gemm2<<<dim3(64, 40, 1), 256, 0, stream>>>(g1, SV, fc1_b, 1024, 256, 256, 3);
    lif_ip<<<4096, 256, 0, stream>>>(ASPK);

    // fc2: binary B (fc1 spikes) -> splitB=1; W-pack reuses Y
    unsigned short* f2_s = (unsigned short*)Y;
    split_pack_k<<<128, 256, 0, stream>>>(fc2_w, f2_s, 256, 1024);
    MArgs g2; g2.W[0] = g2.W[1] = g2.W[2] = f2_s;
    g2.Out[0] = g2.Out[1] = g2.Out[2] = SK;
    g2.bn[0] = g2.bn[1] = g2.bn[2] = fc2_bn;
    mfma_gemm2<<<dim3(16, 40, 1), 256, 0, stream>>>(g2, ASPK, fc2_b, 256, 1024, 256, 1);
    final_k<<<1024, 256, 0, stream>>>(SK, SV, (float*)d_out);
}

// Round 10
// 749.932 us; speedup vs baseline: 1.4607x; 1.0413x over previous
//
#include <hip/hip_runtime.h>
#include <cstdint>
#include <cstddef>

// Problem dims (fixed)
// T=10 B=4 C=256 H=W=16 N=256 HEADS=16 d=16 HID=1024 UC=40 STEP=10 R=4
#define EPSF 1e-5f

typedef __attribute__((ext_vector_type(8))) short short8;
typedef __attribute__((ext_vector_type(4))) float f32x4;

__device__ __forceinline__ unsigned short bf16_rne(float f) {
    unsigned int u = __float_as_uint(f);
    u += 0x7FFFu + ((u >> 16) & 1u);
    return (unsigned short)(u >> 16);
}
__device__ __forceinline__ float bf16f(unsigned short h) {
    return __uint_as_float(((unsigned int)h) << 16);
}

// ---------------------------------------------------------------------------
// Split fp32 W into exact bf16x3 packed in MFMA A-fragment order:
// P[((p*OT + ot)*KT + kt)*512 + lane*8 + j] = split_p(W[ot*16+(lane&15)]
//   [kt*32+(lane>>4)*8+j]). Wave fragment load = 64 lanes x 16B contiguous.
// ---------------------------------------------------------------------------
__device__ __forceinline__ void split_pack_body(
    const float* __restrict__ W, unsigned short* __restrict__ P,
    int O, int K, int idx)
{
    const int OT = O >> 4, KT = K >> 5;
    const int lane = idx & 63, tile = idx >> 6;
    const int kt = tile % KT, ot = tile / KT;
    const int quad = lane >> 4, l15 = lane & 15;
    const int row = ot * 16 + l15, col = kt * 32 + quad * 8;
    const size_t base = ((size_t)ot * KT + kt) * 512 + lane * 8;
    const size_t sOff = (size_t)OT * KT * 512;
#pragma unroll
    for (int j = 0; j < 8; ++j) {
        float v = W[(size_t)row * K + col + j];
        unsigned short h1 = bf16_rne(v);
        float r = v - bf16f(h1);
        unsigned short h2 = bf16_rne(r);
        float r2 = r - bf16f(h2);
        P[base + j] = h1;
        P[sOff + base + j] = h2;
        P[2 * sOff + base + j] = bf16_rne(r2);
    }
}

__global__ __launch_bounds__(256) void split_pack_k(
    const float* __restrict__ W, unsigned short* __restrict__ P, int O, int K)
{
    int idx = blockIdx.x * 256 + threadIdx.x;
    if (idx >= (O * K) >> 3) return;
    split_pack_body(W, P, O, K, idx);
}

struct SplitArgs { const float* W[3]; unsigned short* P[3]; };
__global__ __launch_bounds__(256) void split_pack3_k(SplitArgs sa, int O, int K)
{
    int idx = blockIdx.x * 256 + threadIdx.x;
    if (idx >= (O * K) >> 3) return;
    split_pack_body(sa.W[blockIdx.y], sa.P[blockIdx.y], O, K, idx);
}

// ---------------------------------------------------------------------------
// Split fp32 activations B[s][k][n] into exact bf16x3 packed in MFMA
// B-fragment order: BP[(((s*NT16 + n16)*KT + kt)*64 + lane)*8 + j] =
//   split_p(B[s][kt*32+(lane>>4)*8+j][n16*16+(lane&15)]).
// ---------------------------------------------------------------------------
__global__ __launch_bounds__(256) void bpack_k(
    const float* __restrict__ B, unsigned short* __restrict__ BP,
    int K, int N, int S)
{
    const int KT = K >> 5, NT16 = N >> 4;
    int idx = blockIdx.x * 256 + threadIdx.x;
    if (idx >= S * NT16 * KT * 64) return;
    const int lane = idx & 63;
    int tile = idx >> 6;
    const int kt = tile % KT; tile /= KT;
    const int n16 = tile % NT16; const int s = tile / NT16;
    const int quad = lane >> 4, l15 = lane & 15;
    const size_t base = (size_t)idx * 8;
    const size_t sOff = (size_t)S * NT16 * KT * 512;
    const float* src = B + (size_t)s * K * N + (size_t)(kt * 32 + quad * 8) * N
                         + n16 * 16 + l15;
#pragma unroll
    for (int j = 0; j < 8; ++j) {
        float v = src[(size_t)j * N];
        unsigned short h1 = bf16_rne(v);
        float r = v - bf16f(h1);
        unsigned short h2 = bf16_rne(r);
        float r2 = r - bf16f(h2);
        BP[base + j] = h1;
        BP[sOff + base + j] = h2;
        BP[2 * sOff + base + j] = bf16_rne(r2);
    }
}

struct MArgs { const unsigned short* W[3]; float* Out[3]; const float* bn[3]; };

#define MM(AP, BQ)                                                            \
    {                                                                         \
        _Pragma("unroll") for (int mt = 0; mt < 2; ++mt)                      \
        _Pragma("unroll") for (int nt = 0; nt < 2; ++nt)                      \
            acc[mt][nt] = __builtin_amdgcn_mfma_f32_16x16x32_bf16(            \
                Af[AP][mt], Bf[BQ][nt], acc[mt][nt], 0, 0, 0);                \
    }

// ---------------------------------------------------------------------------
// MFMA GEMM v3: BOTH operands pre-split+packed -> no LDS, no barriers, no
// split VALU in the K-loop. 6-pass product order identical to v2 splitB=3
// (bit-identical accumulation). Block 256 = 4 waves, tile 64x64.
// ---------------------------------------------------------------------------
__global__ __launch_bounds__(256, 4) void mfma_gemm3(
    MArgs a, const unsigned short* __restrict__ BP,
    const float* __restrict__ bias, int O, int K, int N)
{
    const unsigned short* __restrict__ W = a.W[blockIdx.z];
    float* __restrict__ Out = a.Out[blockIdx.z];
    const float* __restrict__ bnp = a.bn[blockIdx.z];
    const int OT = O >> 4, KT = K >> 5, NT16 = N >> 4;
    const size_t sA = (size_t)OT * KT * 512;
    const size_t sB = (size_t)gridDim.y * NT16 * KT * 512;

    const int slice  = blockIdx.y;
    const int tilesn = N >> 6;
    const int to = (blockIdx.x / tilesn) << 6;
    const int tn = (blockIdx.x % tilesn) << 6;
    const int tid = threadIdx.x;
    const int wid = tid >> 6, lane = tid & 63;
    const int quad = lane >> 4, l15 = lane & 15;
    const int wm = (wid >> 1) << 5, wn = (wid & 1) << 5;
    const int oti0 = (to + wm) >> 4;
    const int n160 = (tn + wn) >> 4;

    f32x4 acc[2][2];
#pragma unroll
    for (int mt = 0; mt < 2; ++mt)
#pragma unroll
        for (int nt = 0; nt < 2; ++nt)
#pragma unroll
            for (int r = 0; r < 4; ++r) acc[mt][nt][r] = 0.0f;

    for (int kt = 0; kt < KT; ++kt) {
        short8 Af[3][2], Bf[3][2];
#pragma unroll
        for (int mt = 0; mt < 2; ++mt) {
            const size_t fa = ((size_t)(oti0 + mt) * KT + kt) * 512 + lane * 8;
            Af[0][mt] = *(const short8*)(W + fa);
            Af[1][mt] = *(const short8*)(W + sA + fa);
            Af[2][mt] = *(const short8*)(W + 2 * sA + fa);
        }
#pragma unroll
        for (int nt = 0; nt < 2; ++nt) {
            const size_t fb =
                (((size_t)slice * NT16 + n160 + nt) * KT + kt) * 512 + lane * 8;
            Bf[0][nt] = *(const short8*)(BP + fb);
            Bf[1][nt] = *(const short8*)(BP + sB + fb);
            Bf[2][nt] = *(const short8*)(BP + 2 * sB + fb);
        }
        MM(0, 0) MM(0, 1) MM(1, 0) MM(0, 2) MM(1, 1) MM(2, 0)
    }

    float* Op = Out + (size_t)slice * O * N;
#pragma unroll
    for (int mt = 0; mt < 2; ++mt) {
#pragma unroll
        for (int r = 0; r < 4; ++r) {
            const int o = to + wm + (mt << 4) + (quad << 2) + r;
            float g = bnp[o], bb = bnp[O + o], m = bnp[2 * O + o], vv = bnp[3 * O + o];
            float sq = sqrtf(vv + EPSF);
            float bs = bias ? bias[o] : 0.0f;
#pragma unroll
            for (int nt = 0; nt < 2; ++nt) {
                const int n = tn + wn + (nt << 4) + l15;
                float val = acc[mt][nt][r] + bs;
                Op[(size_t)o * N + n] = (val - m) / sq * g + bb;
            }
        }
    }
}

// ---------------------------------------------------------------------------
// MFMA GEMM v2.1 (binary-spike B): packed A, LDS-staged fp32 B, exact 1-term
// bf16 cvt, 3 passes. Used for proj and fc2.
// ---------------------------------------------------------------------------
__global__ __launch_bounds__(256, 2) void mfma_gemm2(
    MArgs a, const float* __restrict__ X, const float* __restrict__ bias,
    int O, int K, int N)
{
    const unsigned short* __restrict__ W = a.W[blockIdx.z];
    float* __restrict__ Out = a.Out[blockIdx.z];
    const float* __restrict__ bnp = a.bn[blockIdx.z];
    const int OT = O >> 4, KT = K >> 5;
    const size_t sOff = (size_t)OT * KT * 512;

    __shared__ float Bsm[2][32][65];

    const int slice  = blockIdx.y;
    const int tilesn = N >> 6;
    const int to = (blockIdx.x / tilesn) << 6;
    const int tn = (blockIdx.x % tilesn) << 6;
    const int tid = threadIdx.x;
    const int wid = tid >> 6, lane = tid & 63;
    const int quad = lane >> 4, l15 = lane & 15;
    const int wm = (wid >> 1) << 5, wn = (wid & 1) << 5;
    const int oti0 = (to + wm) >> 4;

    f32x4 acc[2][2];
#pragma unroll
    for (int mt = 0; mt < 2; ++mt)
#pragma unroll
        for (int nt = 0; nt < 2; ++nt)
#pragma unroll
            for (int r = 0; r < 4; ++r) acc[mt][nt][r] = 0.0f;

    const float* Xs = X + (size_t)slice * K * N;
    const int nn = tid & 63, r0 = tid >> 6;

    float breg[8];
#pragma unroll
    for (int it = 0; it < 8; ++it)
        breg[it] = Xs[(size_t)(it * 4 + r0) * N + tn + nn];
#pragma unroll
    for (int it = 0; it < 8; ++it)
        Bsm[0][it * 4 + r0][nn] = breg[it];
    __syncthreads();

    for (int kt = 0; kt < KT; ++kt) {
        const int cur = kt & 1;
        if (kt + 1 < KT) {
#pragma unroll
            for (int it = 0; it < 8; ++it)
                breg[it] = Xs[(size_t)((kt + 1) * 32 + it * 4 + r0) * N + tn + nn];
        }
        short8 Af[3][2];
#pragma unroll
        for (int mt = 0; mt < 2; ++mt) {
            const size_t fb = ((size_t)(oti0 + mt) * KT + kt) * 512 + lane * 8;
            Af[0][mt] = *(const short8*)(W + fb);
            Af[1][mt] = *(const short8*)(W + sOff + fb);
            Af[2][mt] = *(const short8*)(W + 2 * sOff + fb);
        }
        short8 Bf[1][2];
#pragma unroll
        for (int nt = 0; nt < 2; ++nt) {
            const int bc = wn + (nt << 4) + l15;
#pragma unroll
            for (int j = 0; j < 8; ++j)
                Bf[0][nt][j] = (short)bf16_rne(Bsm[cur][(quad << 3) + j][bc]);
        }
        MM(0, 0) MM(1, 0) MM(2, 0)
        if (kt + 1 < KT) {
            const int nxt = cur ^ 1;
#pragma unroll
            for (int it = 0; it < 8; ++it)
                Bsm[nxt][it * 4 + r0][nn] = breg[it];
        }
        __syncthreads();
    }

    float* Op = Out + (size_t)slice * O * N;
#pragma unroll
    for (int mt = 0; mt < 2; ++mt) {
#pragma unroll
        for (int r = 0; r < 4; ++r) {
            const int o = to + wm + (mt << 4) + (quad << 2) + r;
            float g = bnp[o], bb = bnp[O + o], m = bnp[2 * O + o], vv = bnp[3 * O + o];
            float sq = sqrtf(vv + EPSF);
            float bs = bias ? bias[o] : 0.0f;
#pragma unroll
            for (int nt = 0; nt < 2; ++nt) {
                const int n = tn + wn + (nt << 4) + l15;
                float val = acc[mt][nt][r] + bs;
                Op[(size_t)o * N + n] = (val - m) / sq * g + bb;
            }
        }
    }
}

// ---------------------------------------------------------------------------
// Weight pre-transpose for tim_up: WT[(t*27+kd*9+q)*48 + g*12 + u] =
//   up_w[(4u+g)*270 + t*27 + kd*9 + q]  (u<10; pad slots 10,11 = 0)
// ---------------------------------------------------------------------------
__global__ __launch_bounds__(256) void wt_k(
    const float* __restrict__ up_w, float* __restrict__ WT)
{
    int idx = blockIdx.x * 256 + threadIdx.x;
    if (idx >= 12960) return;
    int slot = idx % 48, tq = idx / 48;      // tq = t*27 + kd*9 + q
    int g = slot / 12, u = slot % 12;
    float v = 0.0f;
    if (u < 10) v = up_w[(4 * u + g) * 270 + tq];
    WT[idx] = v;
}

// ---------------------------------------------------------------------------
// TIM up conv3d + BN1 + inner LIF, v4.1: half-plane blocks, two t-phases.
// __launch_bounds__(256,6): register-pressure experiment — (256,8) yielded
// VGPR_Count=32 (= acc+vr exactly), suspected AGPR shuffling.
// ---------------------------------------------------------------------------
__global__ __launch_bounds__(256, 6) void tim_up4(
    const float* __restrict__ Y, const float* __restrict__ WT,
    const float* __restrict__ bn1, float* __restrict__ SPK)
{
    __shared__ float smem[5 * 3 * 200];   // [t(5)][cc][10 rows x 20 cols]
    const int c = blockIdx.x;
    const int b = blockIdx.y >> 1, half = blockIdx.y & 1;
    const int tid = threadIdx.x;
    const int lane = tid & 63;
    const int g = __builtin_amdgcn_readfirstlane(tid >> 6);
    const int hb2 = (lane >> 4) << 1;   // 0,2,4,6
    const int wc = lane & 15;

    float acc[2][10];
#pragma unroll
    for (int i = 0; i < 2; ++i)
#pragma unroll
        for (int u = 0; u < 10; ++u) acc[i][u] = 0.0f;

#pragma unroll 1
    for (int ph = 0; ph < 2; ++ph) {
        __syncthreads();
        for (int idx = tid; idx < 3000; idx += 256) {
            int t = ph * 5 + idx / 600, rem = idx % 600;
            int cc = rem / 200, p = rem % 200;
            int rr = p / 20, col = p % 20;
            int h = half * 8 + rr - 1, ww = col - 1;
            int cs = c + cc - 1;
            float v = 0.0f;
            if (cs >= 0 && cs < 256 && h >= 0 && h < 16 && ww >= 0 && ww < 16)
                v = Y[((t * 4 + b) * 256 + cs) * 256 + h * 16 + ww];
            smem[idx] = v;
        }
        __syncthreads();

#pragma unroll 1
        for (int tt = 0; tt < 5; ++tt) {
            const int t = ph * 5 + tt;
#pragma unroll
            for (int kd = 0; kd < 3; ++kd) {
                const float* sp = &smem[tt * 600 + kd * 200 + hb2 * 20 + wc];
                float vr[4][3];
#pragma unroll
                for (int r = 0; r < 4; ++r)
#pragma unroll
                    for (int kc = 0; kc < 3; ++kc)
                        vr[r][kc] = sp[r * 20 + kc];
#pragma unroll
                for (int q = 0; q < 9; ++q) {
                    const int kh = q / 3, kw = q % 3;
                    const float4* wp =
                        (const float4*)&WT[(t * 27 + kd * 9 + q) * 48 + g * 12];
                    float4 w0 = wp[0], w1 = wp[1];
                    float4 w2 = wp[2];
                    float wr[10] = {w0.x, w0.y, w0.z, w0.w, w1.x,
                                    w1.y, w1.z, w1.w, w2.x, w2.y};
#pragma unroll
                    for (int u = 0; u < 10; ++u)
#pragma unroll
                        for (int i = 0; i < 2; ++i)
                            acc[i][u] = fmaf(wr[u], vr[i + kh][kw], acc[i][u]);
                }
            }
        }
    }

#pragma unroll
    for (int i = 0; i < 2; ++i) {
        const int h = half * 8 + hb2 + i;
        float mem = 0.0f;
#pragma unroll
        for (int s = 0; s < 10; ++s) {
            const int uc = 4 * s + g;
            float ga = bn1[uc], be = bn1[40 + uc], mu = bn1[80 + uc], va = bn1[120 + uc];
            float xv = (acc[i][s] - mu) / sqrtf(va + EPSF) * ga + be;
            mem += (xv - mem) * 0.5f;
            float spk = mem > 1.0f ? 1.0f : 0.0f;
            SPK[(((size_t)b * 40 + uc) * 256 + c) * 256 + h * 16 + wc] = spk;
            mem = spk > 0.0f ? 0.0f : mem;
        }
    }
}

// ---------------------------------------------------------------------------
// TIM down grouped conv3d, t-parallel: grid (c=256, b=4, t=10), block 256.
// ---------------------------------------------------------------------------
__global__ __launch_bounds__(256) void tim_down_pre(
    const float* __restrict__ SPK, const float* __restrict__ w,
    const float* __restrict__ bn2, float* __restrict__ PreY)
{
    __shared__ float smem[4 * 3 * 324];   // [r][cc][18*18]
    const int c = blockIdx.x, b = blockIdx.y, t = blockIdx.z;
    const int tid = threadIdx.x;
    for (int idx = tid; idx < 3888; idx += 256) {
        int r = idx / 972, rem = idx % 972;
        int cc = rem / 324, p = rem % 324;
        int hh = p / 18 - 1, ww = p % 18 - 1;
        int cs = c + cc - 1;
        float v = 0.0f;
        if (cs >= 0 && cs < 256 && hh >= 0 && hh < 16 && ww >= 0 && ww < 16)
            v = SPK[(((size_t)b * 40 + 4 * t + r) * 256 + cs) * 256 + hh * 16 + ww];
        smem[idx] = v;
    }
    __syncthreads();
    const int h = tid >> 4, wq = tid & 15;
    float a = 0.0f;
#pragma unroll
    for (int r = 0; r < 4; ++r)
#pragma unroll
        for (int kd = 0; kd < 3; ++kd) {
            const float* wp = w + ((t * 4 + r) * 3 + kd) * 9;
#pragma unroll
            for (int kh = 0; kh < 3; ++kh)
#pragma unroll
                for (int kw = 0; kw < 3; ++kw)
                    a = fmaf(wp[kh * 3 + kw],
                             smem[r * 972 + kd * 324 + (h + kh) * 18 + (wq + kw)], a);
        }
    a = (a - bn2[20 + t]) / sqrtf(bn2[30 + t] + EPSF) * bn2[t] + bn2[10 + t];
    PreY[((t * 4 + b) * 256 + c) * 256 + tid] = a;
}

// LIF over T (vth=1) on PreY (stride 262144), writes binary spikes to S.
__global__ __launch_bounds__(256) void lif_down(
    const float* __restrict__ PreY, float* __restrict__ S)
{
    const int idx = blockIdx.x * 256 + threadIdx.x;
    float mem = 0.0f;
    for (int t = 0; t < 10; ++t) {
        float v = PreY[t * 262144 + idx];
        mem += (v - mem) * 0.5f;
        float spk = mem > 1.0f ? 1.0f : 0.0f;
        S[t * 262144 + idx] = spk;
        mem = spk > 0.0f ? 0.0f : mem;
    }
}

// ---------------------------------------------------------------------------
// ktv[t,b,hd,j,j2] = sum_n K[..j,n] * V[..j2,n]  (exact integer dots)
// ---------------------------------------------------------------------------
__global__ __launch_bounds__(256) void ktv_k(
    const float* __restrict__ SK, const float* __restrict__ SV,
    float* __restrict__ KTV)
{
    __shared__ float ks[16 * 257], vs[16 * 257];
    const int bi = blockIdx.x;
    const int t = bi >> 6, b = (bi >> 4) & 3, hd = bi & 15;
    const int tid = threadIdx.x;
    for (int i = tid; i < 4096; i += 256) {
        int row = i >> 8, col = i & 255;
        ks[row * 257 + col] = SK[((t * 4 + b) * 256 + hd * 16 + row) * 256 + col];
        vs[row * 257 + col] = SV[((t * 4 + b) * 256 + hd * 16 + row) * 256 + col];
    }
    __syncthreads();
    const int j = tid >> 4, j2 = tid & 15;
    float a0 = 0.0f, a1 = 0.0f, a2 = 0.0f, a3 = 0.0f;
#pragma unroll 4
    for (int n = 0; n < 256; n += 4) {
        a0 = fmaf(ks[j * 257 + n + 0], vs[j2 * 257 + n + 0], a0);
        a1 = fmaf(ks[j * 257 + n + 1], vs[j2 * 257 + n + 1], a1);
        a2 = fmaf(ks[j * 257 + n + 2], vs[j2 * 257 + n + 2], a2);
        a3 = fmaf(ks[j * 257 + n + 3], vs[j2 * 257 + n + 3], a3);
    }
    KTV[((t * 4 + b) * 16 + hd) * 256 + tid] = (a0 + a1) + (a2 + a3);
}

// ---------------------------------------------------------------------------
// o = q @ ktv * 0.25 (exact) fused with attn_lif (vth=0.5) -> spikes (t,b,c,n)
// ---------------------------------------------------------------------------
__global__ __launch_bounds__(256) void attn_k(
    const float* __restrict__ SQ, const float* __restrict__ KTV,
    float* __restrict__ OSPK)
{
    __shared__ float kt[2560];    // [t][j*16+j2]
    __shared__ float qs[16 * 17]; // [nl][j], padded
    const int x = blockIdx.x;
    const int b = x >> 8, hd = (x >> 4) & 15, ng = x & 15;
    const int tid = threadIdx.x;
    const int j2 = tid >> 4, nl = tid & 15;
    const int n = ng * 16 + nl;
    for (int i = tid; i < 2560; i += 256) {
        int t = i >> 8;
        kt[i] = KTV[((t * 4 + b) * 16 + hd) * 256 + (i & 255)];
    }
    float mem = 0.0f;
    for (int t = 0; t < 10; ++t) {
        __syncthreads();
        qs[nl * 17 + j2] = SQ[((t * 4 + b) * 256 + hd * 16 + j2) * 256 + n];
        __syncthreads();
        float a = 0.0f;
#pragma unroll
        for (int j = 0; j < 16; ++j)
            a = fmaf(qs[nl * 17 + j], kt[t * 256 + j * 16 + j2], a);
        a *= 0.25f;
        mem += (a - mem) * 0.5f;
        float spk = mem > 0.5f ? 1.0f : 0.0f;
        OSPK[((t * 4 + b) * 256 + hd * 16 + j2) * 256 + n] = spk;
        mem = spk > 0.0f ? 0.0f : mem;
    }
}

// LIF over T (vth=1) on P, then H = x + spikes. Per-t slice 262,144.
__global__ __launch_bounds__(256) void ssa_lif_res(
    const float* __restrict__ P, const float* __restrict__ x,
    float* __restrict__ H)
{
    const int idx = blockIdx.x * 256 + threadIdx.x;
    float mem = 0.0f;
    for (int t = 0; t < 10; ++t) {
        float v = P[t * 262144 + idx];
        mem += (v - mem) * 0.5f;
        float spk = mem > 1.0f ? 1.0f : 0.0f;
        H[t * 262144 + idx] = x[t * 262144 + idx] + spk;
        mem = spk > 0.0f ? 0.0f : mem;
    }
}

// In-place LIF over T (vth=1), per-t slice 1,048,576 (fc1 activations).
__global__ __launch_bounds__(256) void lif_ip(float* __restrict__ A)
{
    const int idx = blockIdx.x * 256 + threadIdx.x;
    float mem = 0.0f;
    for (int t = 0; t < 10; ++t) {
        float v = A[t * 1048576 + idx];
        mem += (v - mem) * 0.5f;
        float spk = mem > 1.0f ? 1.0f : 0.0f;
        A[t * 1048576 + idx] = spk;
        mem = spk > 0.0f ? 0.0f : mem;
    }
}

// out = H + lif(P) over T (vth=1). Per-t slice 262,144.
__global__ __launch_bounds__(256) void final_k(
    const float* __restrict__ P, const float* __restrict__ H,
    float* __restrict__ out)
{
    const int idx = blockIdx.x * 256 + threadIdx.x;
    float mem = 0.0f;
    for (int t = 0; t < 10; ++t) {
        float v = P[t * 262144 + idx];
        mem += (v - mem) * 0.5f;
        float spk = mem > 1.0f ? 1.0f : 0.0f;
        out[t * 262144 + idx] = H[t * 262144 + idx] + spk;
        mem = spk > 0.0f ? 0.0f : mem;
    }
}

// ---------------------------------------------------------------------------
extern "C" void kernel_launch(void* const* d_in, const int* in_sizes, int n_in,
                              void* d_out, int out_size, void* d_ws, size_t ws_size,
                              hipStream_t stream)
{
    const float* x        = (const float*)d_in[0];
    const float* q_w      = (const float*)d_in[1];
    const float* q_bn     = (const float*)d_in[2];
    const float* k_w      = (const float*)d_in[3];
    const float* k_bn     = (const float*)d_in[4];
    const float* v_w      = (const float*)d_in[5];
    const float* v_bn     = (const float*)d_in[6];
    const float* proj_w   = (const float*)d_in[7];
    const float* proj_bn  = (const float*)d_in[8];
    const float* up_w     = (const float*)d_in[9];
    const float* bn1      = (const float*)d_in[10];
    const float* down_w   = (const float*)d_in[11];
    const float* bn2      = (const float*)d_in[12];
    const float* fc1_w    = (const float*)d_in[13];
    const float* fc1_b    = (const float*)d_in[14];
    const float* fc1_bn   = (const float*)d_in[15];
    const float* fc2_w    = (const float*)d_in[16];
    const float* fc2_b    = (const float*)d_in[17];
    const float* fc2_bn   = (const float*)d_in[18];

    float* ws   = (float*)d_ws;
    float* Y    = ws;                    // 2,621,440  (qkv Y0 / down pre-LIF / attn spikes / fc W-packs)
    float* ASPK = Y + 2621440;           // 10,485,760 (qkv W+B packs / up spikes / fc1 out+spikes / proj W-pack)
    float* SQ   = ASPK + 10485760;       // 2,621,440  (q spikes / proj out / fc1 B-pack lo)
    float* SK   = SQ + 2621440;          // 2,621,440  (qkv Y1 / k spikes / fc1 B-pack hi / fc2 out)
    float* SV   = SK + 2621440;          // 2,621,440  (qkv Y2 / v spikes / H)
    float* KTV  = SV + 2621440;          // 163,840  (WT during tim phase, then ktv)
    float* WT   = KTV;                   // 12,960 <= 163,840; dead before ktv_k runs
    // total ws: 21,135,360 floats = 84.5 MB

    float* Yb[3] = {Y, SK, SV};          // branch BN outputs
    float* Sb[3] = {SQ, SK, SV};         // branch spike outputs

    // qkv W-packs + x B-pack in ASPK (dead until first tim_up4)
    unsigned short* qs_s = (unsigned short*)ASPK;      // 196,608 halves each
    unsigned short* ks_s = qs_s + 196608;
    unsigned short* vs_s = qs_s + 393216;
    unsigned short* xp_s = qs_s + 589824;              // 7,864,320 halves

    wt_k<<<51, 256, 0, stream>>>(up_w, WT);
    SplitArgs sa;
    sa.W[0] = q_w; sa.W[1] = k_w; sa.W[2] = v_w;
    sa.P[0] = qs_s; sa.P[1] = ks_s; sa.P[2] = vs_s;
    split_pack3_k<<<dim3(32, 3), 256, 0, stream>>>(sa, 256, 256);
    bpack_k<<<1280, 256, 0, stream>>>(x, xp_s, 256, 256, 40);

    MArgs qkv;
    qkv.W[0] = qs_s;  qkv.W[1] = ks_s;  qkv.W[2] = vs_s;
    qkv.Out[0] = Yb[0]; qkv.Out[1] = Yb[1]; qkv.Out[2] = Yb[2];
    qkv.bn[0] = q_bn; qkv.bn[1] = k_bn; qkv.bn[2] = v_bn;
    mfma_gemm3<<<dim3(16, 40, 3), 256, 0, stream>>>(qkv, xp_s, nullptr, 256, 256, 256);

    for (int br = 0; br < 3; ++br) {
        tim_up4<<<dim3(256, 8), 256, 0, stream>>>(Yb[br], WT, bn1, ASPK);
        tim_down_pre<<<dim3(256, 4, 10), 256, 0, stream>>>(ASPK, down_w, bn2, Y);
        lif_down<<<1024, 256, 0, stream>>>(Y, Sb[br]);
    }

    ktv_k<<<640, 256, 0, stream>>>(SK, SV, KTV);
    attn_k<<<1024, 256, 0, stream>>>(SQ, KTV, Y);               // Y <- attn spikes

    // proj: binary B (attn spikes) -> mfma_gemm2; W-pack in ASPK (dead now)
    unsigned short* pj_s = (unsigned short*)ASPK;
    split_pack_k<<<32, 256, 0, stream>>>(proj_w, pj_s, 256, 256);
    MArgs gp; gp.W[0] = gp.W[1] = gp.W[2] = pj_s;
    gp.Out[0] = gp.Out[1] = gp.Out[2] = SQ;
    gp.bn[0] = gp.bn[1] = gp.bn[2] = proj_bn;
    mfma_gemm2<<<dim3(16, 40, 1), 256, 0, stream>>>(gp, Y, nullptr, 256, 256, 256);
    ssa_lif_res<<<1024, 256, 0, stream>>>(SQ, x, SV);           // SV <- H

    // fc1: continuous B (H) -> pack into SQ(+SK spillover, both dead);
    // W-pack in Y (attn spikes dead now)
    unsigned short* f1b = (unsigned short*)SQ;                  // 7,864,320 halves
    bpack_k<<<1280, 256, 0, stream>>>(SV, f1b, 256, 256, 40);
    unsigned short* f1_s = (unsigned short*)Y;                  // 786,432 halves
    split_pack_k<<<128, 256, 0, stream>>>(fc1_w, f1_s, 1024, 256);
    MArgs g1; g1.W[0] = g1.W[1] = g1.W[2] = f1_s;
    g1.Out[0] = g1.Out[1] = g1.Out[2] = ASPK;
    g1.bn[0] = g1.bn[1] = g1.bn[2] = fc1_bn;
    mfma_gemm3<<<dim3(64, 40, 1), 256, 0, stream>>>(g1, f1b, fc1_b, 1024, 256, 256);
    lif_ip<<<4096, 256, 0, stream>>>(ASPK);

    // fc2: binary B (fc1 spikes) -> mfma_gemm2; W-pack reuses Y
    unsigned short* f2_s = (unsigned short*)Y;
    split_pack_k<<<128, 256, 0, stream>>>(fc2_w, f2_s, 256, 1024);
    MArgs g2; g2.W[0] = g2.W[1] = g2.W[2] = f2_s;
    g2.Out[0] = g2.Out[1] = g2.Out[2] = SK;
    g2.bn[0] = g2.bn[1] = g2.bn[2] = fc2_bn;
    mfma_gemm2<<<dim3(16, 40, 1), 256, 0, stream>>>(g2, ASPK, fc2_b, 256, 1024, 256);
    final_k<<<1024, 256, 0, stream>>>(SK, SV, (float*)d_out);
}

// Round 11
// 682.506 us; speedup vs baseline: 1.6050x; 1.0988x over previous
//
#include <hip/hip_runtime.h>
#include <cstdint>
#include <cstddef>

// Problem dims (fixed)
// T=10 B=4 C=256 H=W=16 N=256 HEADS=16 d=16 HID=1024 UC=40 STEP=10 R=4
#define EPSF 1e-5f

typedef __attribute__((ext_vector_type(8))) short short8;
typedef __attribute__((ext_vector_type(4))) float f32x4;

__device__ __forceinline__ unsigned short bf16_rne(float f) {
    unsigned int u = __float_as_uint(f);
    u += 0x7FFFu + ((u >> 16) & 1u);
    return (unsigned short)(u >> 16);
}
__device__ __forceinline__ float bf16f(unsigned short h) {
    return __uint_as_float(((unsigned int)h) << 16);
}

// ---------------------------------------------------------------------------
// Split fp32 W into exact bf16x3 packed in MFMA A-fragment order:
// P[((p*OT + ot)*KT + kt)*512 + lane*8 + j] = split_p(W[ot*16+(lane&15)]
//   [kt*32+(lane>>4)*8+j]). Wave fragment load = 64 lanes x 16B contiguous.
// ---------------------------------------------------------------------------
__device__ __forceinline__ void split_pack_body(
    const float* __restrict__ W, unsigned short* __restrict__ P,
    int O, int K, int idx)
{
    const int OT = O >> 4, KT = K >> 5;
    const int lane = idx & 63, tile = idx >> 6;
    const int kt = tile % KT, ot = tile / KT;
    const int quad = lane >> 4, l15 = lane & 15;
    const int row = ot * 16 + l15, col = kt * 32 + quad * 8;
    const size_t base = ((size_t)ot * KT + kt) * 512 + lane * 8;
    const size_t sOff = (size_t)OT * KT * 512;
#pragma unroll
    for (int j = 0; j < 8; ++j) {
        float v = W[(size_t)row * K + col + j];
        unsigned short h1 = bf16_rne(v);
        float r = v - bf16f(h1);
        unsigned short h2 = bf16_rne(r);
        float r2 = r - bf16f(h2);
        P[base + j] = h1;
        P[sOff + base + j] = h2;
        P[2 * sOff + base + j] = bf16_rne(r2);
    }
}

__global__ __launch_bounds__(256) void split_pack_k(
    const float* __restrict__ W, unsigned short* __restrict__ P, int O, int K)
{
    int idx = blockIdx.x * 256 + threadIdx.x;
    if (idx >= (O * K) >> 3) return;
    split_pack_body(W, P, O, K, idx);
}

struct SplitArgs { const float* W[3]; unsigned short* P[3]; };
__global__ __launch_bounds__(256) void split_pack3_k(SplitArgs sa, int O, int K)
{
    int idx = blockIdx.x * 256 + threadIdx.x;
    if (idx >= (O * K) >> 3) return;
    split_pack_body(sa.W[blockIdx.y], sa.P[blockIdx.y], O, K, idx);
}

// ---------------------------------------------------------------------------
// Split fp32 activations B[s][k][n] into exact bf16x3 packed in MFMA
// B-fragment order: BP[(((s*NT16 + n16)*KT + kt)*64 + lane)*8 + j] =
//   split_p(B[s][kt*32+(lane>>4)*8+j][n16*16+(lane&15)]).
// ---------------------------------------------------------------------------
__global__ __launch_bounds__(256) void bpack_k(
    const float* __restrict__ B, unsigned short* __restrict__ BP,
    int K, int N, int S)
{
    const int KT = K >> 5, NT16 = N >> 4;
    int idx = blockIdx.x * 256 + threadIdx.x;
    if (idx >= S * NT16 * KT * 64) return;
    const int lane = idx & 63;
    int tile = idx >> 6;
    const int kt = tile % KT; tile /= KT;
    const int n16 = tile % NT16; const int s = tile / NT16;
    const int quad = lane >> 4, l15 = lane & 15;
    const size_t base = (size_t)idx * 8;
    const size_t sOff = (size_t)S * NT16 * KT * 512;
    const float* src = B + (size_t)s * K * N + (size_t)(kt * 32 + quad * 8) * N
                         + n16 * 16 + l15;
#pragma unroll
    for (int j = 0; j < 8; ++j) {
        float v = src[(size_t)j * N];
        unsigned short h1 = bf16_rne(v);
        float r = v - bf16f(h1);
        unsigned short h2 = bf16_rne(r);
        float r2 = r - bf16f(h2);
        BP[base + j] = h1;
        BP[sOff + base + j] = h2;
        BP[2 * sOff + base + j] = bf16_rne(r2);
    }
}

struct MArgs { const unsigned short* W[3]; float* Out[3]; const float* bn[3]; };

#define MM(AP, BQ)                                                            \
    {                                                                         \
        _Pragma("unroll") for (int mt = 0; mt < 2; ++mt)                      \
        _Pragma("unroll") for (int nt = 0; nt < 2; ++nt)                      \
            acc[mt][nt] = __builtin_amdgcn_mfma_f32_16x16x32_bf16(            \
                Af[AP][mt], Bf[BQ][nt], acc[mt][nt], 0, 0, 0);                \
    }

// ---------------------------------------------------------------------------
// MFMA GEMM v3: BOTH operands pre-packed -> no LDS, no barriers, no split
// VALU in the K-loop. nB=3: continuous B, 6-pass (same order as before).
// nB=1: binary-spike B (exact bf16), 3-pass (same order as old mfma_gemm2).
// Block 256 = 4 waves, tile 64x64.
// ---------------------------------------------------------------------------
__global__ __launch_bounds__(256, 4) void mfma_gemm3(
    MArgs a, const unsigned short* __restrict__ BP,
    const float* __restrict__ bias, int O, int K, int N, int nB)
{
    const unsigned short* __restrict__ W = a.W[blockIdx.z];
    float* __restrict__ Out = a.Out[blockIdx.z];
    const float* __restrict__ bnp = a.bn[blockIdx.z];
    const int OT = O >> 4, KT = K >> 5, NT16 = N >> 4;
    const size_t sA = (size_t)OT * KT * 512;
    const size_t sB = (size_t)gridDim.y * NT16 * KT * 512;

    const int slice  = blockIdx.y;
    const int tilesn = N >> 6;
    const int to = (blockIdx.x / tilesn) << 6;
    const int tn = (blockIdx.x % tilesn) << 6;
    const int tid = threadIdx.x;
    const int wid = tid >> 6, lane = tid & 63;
    const int quad = lane >> 4, l15 = lane & 15;
    const int wm = (wid >> 1) << 5, wn = (wid & 1) << 5;
    const int oti0 = (to + wm) >> 4;
    const int n160 = (tn + wn) >> 4;

    f32x4 acc[2][2];
#pragma unroll
    for (int mt = 0; mt < 2; ++mt)
#pragma unroll
        for (int nt = 0; nt < 2; ++nt)
#pragma unroll
            for (int r = 0; r < 4; ++r) acc[mt][nt][r] = 0.0f;

    for (int kt = 0; kt < KT; ++kt) {
        short8 Af[3][2], Bf[3][2];
#pragma unroll
        for (int mt = 0; mt < 2; ++mt) {
            const size_t fa = ((size_t)(oti0 + mt) * KT + kt) * 512 + lane * 8;
            Af[0][mt] = *(const short8*)(W + fa);
            Af[1][mt] = *(const short8*)(W + sA + fa);
            Af[2][mt] = *(const short8*)(W + 2 * sA + fa);
        }
#pragma unroll
        for (int nt = 0; nt < 2; ++nt) {
            const size_t fb =
                (((size_t)slice * NT16 + n160 + nt) * KT + kt) * 512 + lane * 8;
            Bf[0][nt] = *(const short8*)(BP + fb);
            if (nB == 3) {
                Bf[1][nt] = *(const short8*)(BP + sB + fb);
                Bf[2][nt] = *(const short8*)(BP + 2 * sB + fb);
            }
        }
        if (nB == 3) {
            MM(0, 0) MM(0, 1) MM(1, 0) MM(0, 2) MM(1, 1) MM(2, 0)
        } else {
            MM(0, 0) MM(1, 0) MM(2, 0)
        }
    }

    float* Op = Out + (size_t)slice * O * N;
#pragma unroll
    for (int mt = 0; mt < 2; ++mt) {
#pragma unroll
        for (int r = 0; r < 4; ++r) {
            const int o = to + wm + (mt << 4) + (quad << 2) + r;
            float g = bnp[o], bb = bnp[O + o], m = bnp[2 * O + o], vv = bnp[3 * O + o];
            float sq = sqrtf(vv + EPSF);
            float bs = bias ? bias[o] : 0.0f;
#pragma unroll
            for (int nt = 0; nt < 2; ++nt) {
                const int n = tn + wn + (nt << 4) + l15;
                float val = acc[mt][nt][r] + bs;
                Op[(size_t)o * N + n] = (val - m) / sq * g + bb;
            }
        }
    }
}

// ---------------------------------------------------------------------------
// Weight pre-transpose for tim_up: WT[(t*27+kd*9+q)*48 + g*12 + u] =
//   up_w[(4u+g)*270 + t*27 + kd*9 + q]  (u<10; pad slots 10,11 = 0)
// ---------------------------------------------------------------------------
__global__ __launch_bounds__(256) void wt_k(
    const float* __restrict__ up_w, float* __restrict__ WT)
{
    int idx = blockIdx.x * 256 + threadIdx.x;
    if (idx >= 12960) return;
    int slot = idx % 48, tq = idx / 48;      // tq = t*27 + kd*9 + q
    int g = slot / 12, u = slot % 12;
    float v = 0.0f;
    if (u < 10) v = up_w[(4 * u + g) * 270 + tq];
    WT[idx] = v;
}

// ---------------------------------------------------------------------------
// TIM up conv3d + BN1 + inner LIF, v5: merged 3 branches (z), uchar spikes.
// Grid (c=256, b*2=8, br=3), block 256 = 4 waves. (256,8): round-9 best.
// ---------------------------------------------------------------------------
struct TimArgs { const float* Y[3]; };

__global__ __launch_bounds__(256, 8) void tim_up5(
    TimArgs ta, const float* __restrict__ WT,
    const float* __restrict__ bn1, unsigned char* __restrict__ USPK)
{
    __shared__ float smem[5 * 3 * 200];   // [t(5)][cc][10 rows x 20 cols]
    const float* __restrict__ Y = ta.Y[blockIdx.z];
    unsigned char* __restrict__ SPK = USPK + (size_t)blockIdx.z * 10485760;
    const int c = blockIdx.x;
    const int b = blockIdx.y >> 1, half = blockIdx.y & 1;
    const int tid = threadIdx.x;
    const int lane = tid & 63;
    const int g = __builtin_amdgcn_readfirstlane(tid >> 6);
    const int hb2 = (lane >> 4) << 1;   // 0,2,4,6
    const int wc = lane & 15;

    float acc[2][10];
#pragma unroll
    for (int i = 0; i < 2; ++i)
#pragma unroll
        for (int u = 0; u < 10; ++u) acc[i][u] = 0.0f;

#pragma unroll 1
    for (int ph = 0; ph < 2; ++ph) {
        __syncthreads();
        for (int idx = tid; idx < 3000; idx += 256) {
            int t = ph * 5 + idx / 600, rem = idx % 600;
            int cc = rem / 200, p = rem % 200;
            int rr = p / 20, col = p % 20;
            int h = half * 8 + rr - 1, ww = col - 1;
            int cs = c + cc - 1;
            float v = 0.0f;
            if (cs >= 0 && cs < 256 && h >= 0 && h < 16 && ww >= 0 && ww < 16)
                v = Y[((t * 4 + b) * 256 + cs) * 256 + h * 16 + ww];
            smem[idx] = v;
        }
        __syncthreads();

#pragma unroll 1
        for (int tt = 0; tt < 5; ++tt) {
            const int t = ph * 5 + tt;
#pragma unroll
            for (int kd = 0; kd < 3; ++kd) {
                const float* sp = &smem[tt * 600 + kd * 200 + hb2 * 20 + wc];
                float vr[4][3];
#pragma unroll
                for (int r = 0; r < 4; ++r)
#pragma unroll
                    for (int kc = 0; kc < 3; ++kc)
                        vr[r][kc] = sp[r * 20 + kc];
#pragma unroll
                for (int q = 0; q < 9; ++q) {
                    const int kh = q / 3, kw = q % 3;
                    const float4* wp =
                        (const float4*)&WT[(t * 27 + kd * 9 + q) * 48 + g * 12];
                    float4 w0 = wp[0], w1 = wp[1];
                    float4 w2 = wp[2];
                    float wr[10] = {w0.x, w0.y, w0.z, w0.w, w1.x,
                                    w1.y, w1.z, w1.w, w2.x, w2.y};
#pragma unroll
                    for (int u = 0; u < 10; ++u)
#pragma unroll
                        for (int i = 0; i < 2; ++i)
                            acc[i][u] = fmaf(wr[u], vr[i + kh][kw], acc[i][u]);
                }
            }
        }
    }

#pragma unroll
    for (int i = 0; i < 2; ++i) {
        const int h = half * 8 + hb2 + i;
        float mem = 0.0f;
#pragma unroll
        for (int s = 0; s < 10; ++s) {
            const int uc = 4 * s + g;
            float ga = bn1[uc], be = bn1[40 + uc], mu = bn1[80 + uc], va = bn1[120 + uc];
            float xv = (acc[i][s] - mu) / sqrtf(va + EPSF) * ga + be;
            mem += (xv - mem) * 0.5f;
            unsigned char spk = mem > 1.0f ? 1 : 0;
            SPK[(((size_t)b * 40 + uc) * 256 + c) * 256 + h * 16 + wc] = spk;
            mem = spk ? 0.0f : mem;
        }
    }
}

// ---------------------------------------------------------------------------
// TIM down grouped conv3d, merged: grid (c=256, b=4, br*10+t=30), block 256.
// Reads uchar spikes; writes BN2'd pre-LIF floats into PY.p[br].
// ---------------------------------------------------------------------------
struct PtrArgs { float* p[3]; };
struct CPtrArgs { const float* p[3]; };

__global__ __launch_bounds__(256) void tim_down_pre5(
    const unsigned char* __restrict__ USPK, const float* __restrict__ w,
    const float* __restrict__ bn2, PtrArgs PY)
{
    __shared__ float smem[4 * 3 * 324];   // [r][cc][18*18]
    const int br = blockIdx.z / 10, t = blockIdx.z % 10;
    const unsigned char* __restrict__ SPK = USPK + (size_t)br * 10485760;
    float* __restrict__ PreY = PY.p[br];
    const int c = blockIdx.x, b = blockIdx.y;
    const int tid = threadIdx.x;
    for (int idx = tid; idx < 3888; idx += 256) {
        int r = idx / 972, rem = idx % 972;
        int cc = rem / 324, p = rem % 324;
        int hh = p / 18 - 1, ww = p % 18 - 1;
        int cs = c + cc - 1;
        float v = 0.0f;
        if (cs >= 0 && cs < 256 && hh >= 0 && hh < 16 && ww >= 0 && ww < 16)
            v = (float)SPK[(((size_t)b * 40 + 4 * t + r) * 256 + cs) * 256 + hh * 16 + ww];
        smem[idx] = v;
    }
    __syncthreads();
    const int h = tid >> 4, wq = tid & 15;
    float a = 0.0f;
#pragma unroll
    for (int r = 0; r < 4; ++r)
#pragma unroll
        for (int kd = 0; kd < 3; ++kd) {
            const float* wp = w + ((t * 4 + r) * 3 + kd) * 9;
#pragma unroll
            for (int kh = 0; kh < 3; ++kh)
#pragma unroll
                for (int kw = 0; kw < 3; ++kw)
                    a = fmaf(wp[kh * 3 + kw],
                             smem[r * 972 + kd * 324 + (h + kh) * 18 + (wq + kw)], a);
        }
    a = (a - bn2[20 + t]) / sqrtf(bn2[30 + t] + EPSF) * bn2[t] + bn2[10 + t];
    PreY[((t * 4 + b) * 256 + c) * 256 + tid] = a;
}

// Merged LIF over T (vth=1): grid (1024, 3). In-place safe (read-then-write).
__global__ __launch_bounds__(256) void lif_down3(CPtrArgs PY, PtrArgs SB)
{
    const float* __restrict__ PreY = PY.p[blockIdx.y];
    float* __restrict__ S = SB.p[blockIdx.y];
    const int idx = blockIdx.x * 256 + threadIdx.x;
    float mem = 0.0f;
    for (int t = 0; t < 10; ++t) {
        float v = PreY[t * 262144 + idx];
        mem += (v - mem) * 0.5f;
        float spk = mem > 1.0f ? 1.0f : 0.0f;
        S[t * 262144 + idx] = spk;
        mem = spk > 0.0f ? 0.0f : mem;
    }
}

// ---------------------------------------------------------------------------
// ktv[t,b,hd,j,j2] = sum_n K[..j,n] * V[..j2,n]  (exact integer dots)
// ---------------------------------------------------------------------------
__global__ __launch_bounds__(256) void ktv_k(
    const float* __restrict__ SK, const float* __restrict__ SV,
    float* __restrict__ KTV)
{
    __shared__ float ks[16 * 257], vs[16 * 257];
    const int bi = blockIdx.x;
    const int t = bi >> 6, b = (bi >> 4) & 3, hd = bi & 15;
    const int tid = threadIdx.x;
    for (int i = tid; i < 4096; i += 256) {
        int row = i >> 8, col = i & 255;
        ks[row * 257 + col] = SK[((t * 4 + b) * 256 + hd * 16 + row) * 256 + col];
        vs[row * 257 + col] = SV[((t * 4 + b) * 256 + hd * 16 + row) * 256 + col];
    }
    __syncthreads();
    const int j = tid >> 4, j2 = tid & 15;
    float a0 = 0.0f, a1 = 0.0f, a2 = 0.0f, a3 = 0.0f;
#pragma unroll 4
    for (int n = 0; n < 256; n += 4) {
        a0 = fmaf(ks[j * 257 + n + 0], vs[j2 * 257 + n + 0], a0);
        a1 = fmaf(ks[j * 257 + n + 1], vs[j2 * 257 + n + 1], a1);
        a2 = fmaf(ks[j * 257 + n + 2], vs[j2 * 257 + n + 2], a2);
        a3 = fmaf(ks[j * 257 + n + 3], vs[j2 * 257 + n + 3], a3);
    }
    KTV[((t * 4 + b) * 16 + hd) * 256 + tid] = (a0 + a1) + (a2 + a3);
}

// ---------------------------------------------------------------------------
// o = q @ ktv * 0.25 (exact) + attn_lif (vth=0.5) -> spikes written DIRECTLY
// as bf16 B-fragment pack (proj's MFMA input). Layout (slices=t*4+b, K=256,
// N=256): addr = ((slice*16 + n16)*8 + kt)*512 + lane*8 + j.
// ---------------------------------------------------------------------------
__global__ __launch_bounds__(256) void attn_k2(
    const float* __restrict__ SQ, const float* __restrict__ KTV,
    unsigned short* __restrict__ PSPK)
{
    __shared__ float kt[2560];    // [t][j*16+j2]
    __shared__ float qs[16 * 17]; // [nl][j], padded
    const int x = blockIdx.x;
    const int b = x >> 8, hd = (x >> 4) & 15, ng = x & 15;
    const int tid = threadIdx.x;
    const int j2 = tid >> 4, nl = tid & 15;
    const int n = ng * 16 + nl;
    for (int i = tid; i < 2560; i += 256) {
        int t = i >> 8;
        kt[i] = KTV[((t * 4 + b) * 16 + hd) * 256 + (i & 255)];
    }
    // fragment coords for k-index c = hd*16 + j2
    const int c = hd * 16 + j2;
    const int ktile = c >> 5, quad = (c >> 3) & 3, jj = c & 7;
    const int lane = quad * 16 + nl;
    float mem = 0.0f;
    for (int t = 0; t < 10; ++t) {
        __syncthreads();
        qs[nl * 17 + j2] = SQ[((t * 4 + b) * 256 + hd * 16 + j2) * 256 + n];
        __syncthreads();
        float a = 0.0f;
#pragma unroll
        for (int j = 0; j < 16; ++j)
            a = fmaf(qs[nl * 17 + j], kt[t * 256 + j * 16 + j2], a);
        a *= 0.25f;
        mem += (a - mem) * 0.5f;
        float spk = mem > 0.5f ? 1.0f : 0.0f;
        PSPK[((((size_t)(t * 4 + b) * 16 + ng) * 8 + ktile) * 512) + lane * 8 + jj] =
            spk > 0.0f ? (unsigned short)0x3F80 : (unsigned short)0;
        mem = spk > 0.0f ? 0.0f : mem;
    }
}

// LIF over T (vth=1) on P, then H = x + spikes. Per-t slice 262,144.
__global__ __launch_bounds__(256) void ssa_lif_res(
    const float* __restrict__ P, const float* __restrict__ x,
    float* __restrict__ H)
{
    const int idx = blockIdx.x * 256 + threadIdx.x;
    float mem = 0.0f;
    for (int t = 0; t < 10; ++t) {
        float v = P[t * 262144 + idx];
        mem += (v - mem) * 0.5f;
        float spk = mem > 1.0f ? 1.0f : 0.0f;
        H[t * 262144 + idx] = x[t * 262144 + idx] + spk;
        mem = spk > 0.0f ? 0.0f : mem;
    }
}

// ---------------------------------------------------------------------------
// LIF over T (vth=1) on fc1 activations (t,b,1024,hw) + DIRECT bf16
// B-fragment pack (fc2's MFMA input; slices=t*4+b, K=1024, N=256):
// addr = ((slice*16 + n16)*32 + kt)*512 + lane*8 + j.
// ---------------------------------------------------------------------------
__global__ __launch_bounds__(256) void lif_pack(
    const float* __restrict__ A, unsigned short* __restrict__ PB)
{
    const int idx = blockIdx.x * 256 + threadIdx.x;
    const int b = idx >> 18, rem = idx & 262143;
    const int hid = rem >> 8, hw = rem & 255;
    const int ktile = hid >> 5, quad = (hid >> 3) & 3, jj = hid & 7;
    const int n16 = hw >> 4, l15 = hw & 15;
    const int lane = quad * 16 + l15;
    float mem = 0.0f;
    for (int t = 0; t < 10; ++t) {
        float v = A[t * 1048576 + idx];
        mem += (v - mem) * 0.5f;
        float spk = mem > 1.0f ? 1.0f : 0.0f;
        PB[((((size_t)(t * 4 + b) * 16 + n16) * 32 + ktile) * 512) + lane * 8 + jj] =
            spk > 0.0f ? (unsigned short)0x3F80 : (unsigned short)0;
        mem = spk > 0.0f ? 0.0f : mem;
    }
}

// out = H + lif(P) over T (vth=1). Per-t slice 262,144.
__global__ __launch_bounds__(256) void final_k(
    const float* __restrict__ P, const float* __restrict__ H,
    float* __restrict__ out)
{
    const int idx = blockIdx.x * 256 + threadIdx.x;
    float mem = 0.0f;
    for (int t = 0; t < 10; ++t) {
        float v = P[t * 262144 + idx];
        mem += (v - mem) * 0.5f;
        float spk = mem > 1.0f ? 1.0f : 0.0f;
        out[t * 262144 + idx] = H[t * 262144 + idx] + spk;
        mem = spk > 0.0f ? 0.0f : mem;
    }
}

// ---------------------------------------------------------------------------
extern "C" void kernel_launch(void* const* d_in, const int* in_sizes, int n_in,
                              void* d_out, int out_size, void* d_ws, size_t ws_size,
                              hipStream_t stream)
{
    const float* x        = (const float*)d_in[0];
    const float* q_w      = (const float*)d_in[1];
    const float* q_bn     = (const float*)d_in[2];
    const float* k_w      = (const float*)d_in[3];
    const float* k_bn     = (const float*)d_in[4];
    const float* v_w      = (const float*)d_in[5];
    const float* v_bn     = (const float*)d_in[6];
    const float* proj_w   = (const float*)d_in[7];
    const float* proj_bn  = (const float*)d_in[8];
    const float* up_w     = (const float*)d_in[9];
    const float* bn1      = (const float*)d_in[10];
    const float* down_w   = (const float*)d_in[11];
    const float* bn2      = (const float*)d_in[12];
    const float* fc1_w    = (const float*)d_in[13];
    const float* fc1_b    = (const float*)d_in[14];
    const float* fc1_bn   = (const float*)d_in[15];
    const float* fc2_w    = (const float*)d_in[16];
    const float* fc2_b    = (const float*)d_in[17];
    const float* fc2_bn   = (const float*)d_in[18];

    float* ws   = (float*)d_ws;
    float* Y    = ws;                    // 2,621,440 fl (qkv Y0 / PreY0 / proj PSPK / fc W-packs)
    float* ASPK = Y + 2621440;           // 10,485,760 fl (qkv W+B packs / uchar up-spikes / proj W-pack / fc1 out / fc2 out)
    float* SQ   = ASPK + 10485760;       // 2,621,440 fl (q spikes / proj out / fc1 B-pack / fc2 B-pack)
    float* SK   = SQ + 2621440;          // 2,621,440 fl (qkv Y1 / PreY1 / k spikes / pack spill)
    float* SV   = SK + 2621440;          // 2,621,440 fl (qkv Y2 / PreY2 / v spikes / H)
    float* KTV  = SV + 2621440;          // 163,840 fl (WT during tim phase, then ktv)
    float* WT   = KTV;                   // 12,960 <= 163,840; dead before ktv_k
    // total ws: 21,135,360 floats = 84.5 MB

    // qkv W-packs + x B-pack in ASPK (dead until tim_up5 needs it for spikes)
    unsigned short* qs_s = (unsigned short*)ASPK;      // 196,608 halves each
    unsigned short* ks_s = qs_s + 196608;
    unsigned short* vs_s = qs_s + 393216;
    unsigned short* xp_s = qs_s + 589824;              // 7,864,320 halves

    wt_k<<<51, 256, 0, stream>>>(up_w, WT);
    SplitArgs sa;
    sa.W[0] = q_w; sa.W[1] = k_w; sa.W[2] = v_w;
    sa.P[0] = qs_s; sa.P[1] = ks_s; sa.P[2] = vs_s;
    split_pack3_k<<<dim3(32, 3), 256, 0, stream>>>(sa, 256, 256);
    bpack_k<<<1280, 256, 0, stream>>>(x, xp_s, 256, 256, 40);

    MArgs qkv;
    qkv.W[0] = qs_s;  qkv.W[1] = ks_s;  qkv.W[2] = vs_s;
    qkv.Out[0] = Y; qkv.Out[1] = SK; qkv.Out[2] = SV;
    qkv.bn[0] = q_bn; qkv.bn[1] = k_bn; qkv.bn[2] = v_bn;
    mfma_gemm3<<<dim3(16, 40, 3), 256, 0, stream>>>(qkv, xp_s, nullptr, 256, 256, 256, 3);

    // merged TIM phase: uchar up-spikes (3 x 10,485,760 B = 31.5 MB) in ASPK
    unsigned char* USPK = (unsigned char*)ASPK;
    TimArgs ta; ta.Y[0] = Y; ta.Y[1] = SK; ta.Y[2] = SV;
    tim_up5<<<dim3(256, 8, 3), 256, 0, stream>>>(ta, WT, bn1, USPK);

    PtrArgs PY; PY.p[0] = Y; PY.p[1] = SK; PY.p[2] = SV;
    tim_down_pre5<<<dim3(256, 4, 30), 256, 0, stream>>>(USPK, down_w, bn2, PY);

    CPtrArgs PYc; PYc.p[0] = Y; PYc.p[1] = SK; PYc.p[2] = SV;
    PtrArgs SB; SB.p[0] = SQ; SB.p[1] = SK; SB.p[2] = SV;   // br1/2 in-place (safe)
    lif_down3<<<dim3(1024, 3), 256, 0, stream>>>(PYc, SB);

    ktv_k<<<640, 256, 0, stream>>>(SK, SV, KTV);
    unsigned short* PSPK = (unsigned short*)Y;              // PreY0 dead after lif_down3
    attn_k2<<<1024, 256, 0, stream>>>(SQ, KTV, PSPK);       // packed attn spikes

    // proj: packed binary B -> mfma_gemm3 nB=1; W-pack in ASPK (USPK dead)
    unsigned short* pj_s = (unsigned short*)ASPK;
    split_pack_k<<<32, 256, 0, stream>>>(proj_w, pj_s, 256, 256);
    MArgs gp; gp.W[0] = gp.W[1] = gp.W[2] = pj_s;
    gp.Out[0] = gp.Out[1] = gp.Out[2] = SQ;                 // q-spikes dead after attn
    gp.bn[0] = gp.bn[1] = gp.bn[2] = proj_bn;
    mfma_gemm3<<<dim3(16, 40, 1), 256, 0, stream>>>(gp, PSPK, nullptr, 256, 256, 256, 1);
    ssa_lif_res<<<1024, 256, 0, stream>>>(SQ, x, SV);       // SV <- H (v-spikes dead)

    // fc1: continuous B (H) -> bpack into SQ(+SK spill, both dead); W-pack in Y
    unsigned short* f1b = (unsigned short*)SQ;              // 7,864,320 halves
    bpack_k<<<1280, 256, 0, stream>>>(SV, f1b, 256, 256, 40);
    unsigned short* f1_s = (unsigned short*)Y;              // PSPK dead after proj
    split_pack_k<<<128, 256, 0, stream>>>(fc1_w, f1_s, 1024, 256);
    MArgs g1; g1.W[0] = g1.W[1] = g1.W[2] = f1_s;
    g1.Out[0] = g1.Out[1] = g1.Out[2] = ASPK;               // pj_s dead
    g1.bn[0] = g1.bn[1] = g1.bn[2] = fc1_bn;
    mfma_gemm3<<<dim3(64, 40, 1), 256, 0, stream>>>(g1, f1b, fc1_b, 1024, 256, 256, 3);

    // fc2: LIF + pack fused -> PB2 in SQ+SK (f1b dead after fc1)
    unsigned short* PB2 = (unsigned short*)SQ;              // 10,485,760 halves (21 MB)
    lif_pack<<<4096, 256, 0, stream>>>(ASPK, PB2);
    unsigned short* f2_s = (unsigned short*)Y;              // f1_s dead
    split_pack_k<<<128, 256, 0, stream>>>(fc2_w, f2_s, 256, 1024);
    MArgs g2; g2.W[0] = g2.W[1] = g2.W[2] = f2_s;
    g2.Out[0] = g2.Out[1] = g2.Out[2] = ASPK;               // fc1-out dead after lif_pack
    g2.bn[0] = g2.bn[1] = g2.bn[2] = fc2_bn;
    mfma_gemm3<<<dim3(16, 40, 1), 256, 0, stream>>>(g2, PB2, fc2_b, 256, 1024, 256, 1);
    final_k<<<1024, 256, 0, stream>>>(ASPK, SV, (float*)d_out);
}

// Round 12
// 672.981 us; speedup vs baseline: 1.6278x; 1.0142x over previous
//
#include <hip/hip_runtime.h>
#include <cstdint>
#include <cstddef>

// Problem dims (fixed)
// T=10 B=4 C=256 H=W=16 N=256 HEADS=16 d=16 HID=1024 UC=40 STEP=10 R=4
#define EPSF 1e-5f

typedef __attribute__((ext_vector_type(8))) short short8;
typedef __attribute__((ext_vector_type(4))) float f32x4;

__device__ __forceinline__ unsigned short bf16_rne(float f) {
    unsigned int u = __float_as_uint(f);
    u += 0x7FFFu + ((u >> 16) & 1u);
    return (unsigned short)(u >> 16);
}
__device__ __forceinline__ float bf16f(unsigned short h) {
    return __uint_as_float(((unsigned int)h) << 16);
}

// ---------------------------------------------------------------------------
// Split fp32 W into exact bf16x3 packed in MFMA A-fragment order (GEMMs):
// P[((p*OT + ot)*KT + kt)*512 + lane*8 + j]
// ---------------------------------------------------------------------------
__device__ __forceinline__ void split_pack_body(
    const float* __restrict__ W, unsigned short* __restrict__ P,
    int O, int K, int idx)
{
    const int OT = O >> 4, KT = K >> 5;
    const int lane = idx & 63, tile = idx >> 6;
    const int kt = tile % KT, ot = tile / KT;
    const int quad = lane >> 4, l15 = lane & 15;
    const int row = ot * 16 + l15, col = kt * 32 + quad * 8;
    const size_t base = ((size_t)ot * KT + kt) * 512 + lane * 8;
    const size_t sOff = (size_t)OT * KT * 512;
#pragma unroll
    for (int j = 0; j < 8; ++j) {
        float v = W[(size_t)row * K + col + j];
        unsigned short h1 = bf16_rne(v);
        float r = v - bf16f(h1);
        unsigned short h2 = bf16_rne(r);
        float r2 = r - bf16f(h2);
        P[base + j] = h1;
        P[sOff + base + j] = h2;
        P[2 * sOff + base + j] = bf16_rne(r2);
    }
}

__global__ __launch_bounds__(256) void split_pack_k(
    const float* __restrict__ W, unsigned short* __restrict__ P, int O, int K)
{
    int idx = blockIdx.x * 256 + threadIdx.x;
    if (idx >= (O * K) >> 3) return;
    split_pack_body(W, P, O, K, idx);
}

struct SplitArgs { const float* W[3]; unsigned short* P[3]; };
__global__ __launch_bounds__(256) void split_pack3_k(SplitArgs sa, int O, int K)
{
    int idx = blockIdx.x * 256 + threadIdx.x;
    if (idx >= (O * K) >> 3) return;
    split_pack_body(sa.W[blockIdx.y], sa.P[blockIdx.y], O, K, idx);
}

// ---------------------------------------------------------------------------
// Split fp32 activations B[s][k][n] into bf16x3 packed in MFMA B-frag order.
// ---------------------------------------------------------------------------
__global__ __launch_bounds__(256) void bpack_k(
    const float* __restrict__ B, unsigned short* __restrict__ BP,
    int K, int N, int S)
{
    const int KT = K >> 5, NT16 = N >> 4;
    int idx = blockIdx.x * 256 + threadIdx.x;
    if (idx >= S * NT16 * KT * 64) return;
    const int lane = idx & 63;
    int tile = idx >> 6;
    const int kt = tile % KT; tile /= KT;
    const int n16 = tile % NT16; const int s = tile / NT16;
    const int quad = lane >> 4, l15 = lane & 15;
    const size_t base = (size_t)idx * 8;
    const size_t sOff = (size_t)S * NT16 * KT * 512;
    const float* src = B + (size_t)s * K * N + (size_t)(kt * 32 + quad * 8) * N
                         + n16 * 16 + l15;
#pragma unroll
    for (int j = 0; j < 8; ++j) {
        float v = src[(size_t)j * N];
        unsigned short h1 = bf16_rne(v);
        float r = v - bf16f(h1);
        unsigned short h2 = bf16_rne(r);
        float r2 = r - bf16f(h2);
        BP[base + j] = h1;
        BP[sOff + base + j] = h2;
        BP[2 * sOff + base + j] = bf16_rne(r2);
    }
}

struct MArgs { const unsigned short* W[3]; float* Out[3]; const float* bn[3]; };

#define MM(AP, BQ)                                                            \
    {                                                                         \
        _Pragma("unroll") for (int mt = 0; mt < 2; ++mt)                      \
        _Pragma("unroll") for (int nt = 0; nt < 2; ++nt)                      \
            acc[mt][nt] = __builtin_amdgcn_mfma_f32_16x16x32_bf16(            \
                Af[AP][mt], Bf[BQ][nt], acc[mt][nt], 0, 0, 0);                \
    }

// ---------------------------------------------------------------------------
// MFMA GEMM v3: both operands pre-packed; no LDS/barriers in K-loop.
// ---------------------------------------------------------------------------
__global__ __launch_bounds__(256, 4) void mfma_gemm3(
    MArgs a, const unsigned short* __restrict__ BP,
    const float* __restrict__ bias, int O, int K, int N, int nB)
{
    const unsigned short* __restrict__ W = a.W[blockIdx.z];
    float* __restrict__ Out = a.Out[blockIdx.z];
    const float* __restrict__ bnp = a.bn[blockIdx.z];
    const int OT = O >> 4, KT = K >> 5, NT16 = N >> 4;
    const size_t sA = (size_t)OT * KT * 512;
    const size_t sB = (size_t)gridDim.y * NT16 * KT * 512;

    const int slice  = blockIdx.y;
    const int tilesn = N >> 6;
    const int to = (blockIdx.x / tilesn) << 6;
    const int tn = (blockIdx.x % tilesn) << 6;
    const int tid = threadIdx.x;
    const int wid = tid >> 6, lane = tid & 63;
    const int quad = lane >> 4, l15 = lane & 15;
    const int wm = (wid >> 1) << 5, wn = (wid & 1) << 5;
    const int oti0 = (to + wm) >> 4;
    const int n160 = (tn + wn) >> 4;

    f32x4 acc[2][2];
#pragma unroll
    for (int mt = 0; mt < 2; ++mt)
#pragma unroll
        for (int nt = 0; nt < 2; ++nt)
#pragma unroll
            for (int r = 0; r < 4; ++r) acc[mt][nt][r] = 0.0f;

    for (int kt = 0; kt < KT; ++kt) {
        short8 Af[3][2], Bf[3][2];
#pragma unroll
        for (int mt = 0; mt < 2; ++mt) {
            const size_t fa = ((size_t)(oti0 + mt) * KT + kt) * 512 + lane * 8;
            Af[0][mt] = *(const short8*)(W + fa);
            Af[1][mt] = *(const short8*)(W + sA + fa);
            Af[2][mt] = *(const short8*)(W + 2 * sA + fa);
        }
#pragma unroll
        for (int nt = 0; nt < 2; ++nt) {
            const size_t fb =
                (((size_t)slice * NT16 + n160 + nt) * KT + kt) * 512 + lane * 8;
            Bf[0][nt] = *(const short8*)(BP + fb);
            if (nB == 3) {
                Bf[1][nt] = *(const short8*)(BP + sB + fb);
                Bf[2][nt] = *(const short8*)(BP + 2 * sB + fb);
            }
        }
        if (nB == 3) {
            MM(0, 0) MM(0, 1) MM(1, 0) MM(0, 2) MM(1, 1) MM(2, 0)
        } else {
            MM(0, 0) MM(1, 0) MM(2, 0)
        }
    }

    float* Op = Out + (size_t)slice * O * N;
#pragma unroll
    for (int mt = 0; mt < 2; ++mt) {
#pragma unroll
        for (int r = 0; r < 4; ++r) {
            const int o = to + wm + (mt << 4) + (quad << 2) + r;
            float g = bnp[o], bb = bnp[O + o], m = bnp[2 * O + o], vv = bnp[3 * O + o];
            float sq = sqrtf(vv + EPSF);
            float bs = bias ? bias[o] : 0.0f;
#pragma unroll
            for (int nt = 0; nt < 2; ++nt) {
                const int n = tn + wn + (nt << 4) + l15;
                float val = acc[mt][nt][r] + bs;
                Op[(size_t)o * N + n] = (val - m) / sq * g + bb;
            }
        }
    }
}

// ---------------------------------------------------------------------------
// tim_up weight pack for MFMA conv: A[m=uc(pad 48)][k=t*32+tap(pad 27->32)]
// AP[((p*3+mt)*10 + t)*512 + lane*8 + j]; zero for uc>=40 or tap>=27.
// 1920 threads.
// ---------------------------------------------------------------------------
__global__ __launch_bounds__(256) void wpack6_k(
    const float* __restrict__ up_w, unsigned short* __restrict__ AP)
{
    int idx = blockIdx.x * 256 + threadIdx.x;
    if (idx >= 1920) return;
    const int lane = idx & 63, rest = idx >> 6;
    const int t = rest % 10, mt = rest / 10;
    const int quad = lane >> 4, l15 = lane & 15;
    const int uc = mt * 16 + l15;
    const size_t base = ((size_t)mt * 10 + t) * 512 + lane * 8;
#pragma unroll
    for (int j = 0; j < 8; ++j) {
        int tap = quad * 8 + j;
        float v = 0.0f;
        if (uc < 40 && tap < 27) v = up_w[uc * 270 + t * 27 + tap];
        unsigned short h1 = bf16_rne(v);
        float r = v - bf16f(h1);
        unsigned short h2 = bf16_rne(r);
        float r2 = r - bf16f(h2);
        AP[base + j] = h1;
        AP[15360 + base + j] = h2;
        AP[30720 + base + j] = bf16_rne(r2);
    }
}

// ---------------------------------------------------------------------------
// TIM up conv3d as MFMA + BN1 + inner LIF, v6.
// Grid (c=256, b=4, br=3), block 256 = 4 waves; full 256-pixel plane/block.
// im2col GEMM: M=48(uc pad), K=10x32 taps (27 real), N=256 pixels.
// Wave w owns n-groups {4w..4w+3} (pixel rows h=ng, cols=l15).
// Y staged fp32 in LDS (2 t-phases), bf16x3 split in-register, 6-pass MM
// (same product set/order class as the passing GEMMs). C -> LDS transpose
// (stride 257) -> per-pixel BN1+LIF -> uchar spikes (layout unchanged).
// ---------------------------------------------------------------------------
struct TimArgs { const float* Y[3]; };

__global__ __launch_bounds__(256, 2) void tim_up6(
    TimArgs ta, const unsigned short* __restrict__ AP,
    const float* __restrict__ bn1, unsigned char* __restrict__ USPK)
{
    // union: staging (5 t x 3 kd x 18 rows x 20 cols = 5400 f) | C 48x257=12336 f
    __shared__ float smem[12336];
    const float* __restrict__ Y = ta.Y[blockIdx.z];
    unsigned char* __restrict__ SPK = USPK + (size_t)blockIdx.z * 10485760;
    const int c = blockIdx.x, b = blockIdx.y;
    const int tid = threadIdx.x;
    const int wid = tid >> 6, lane = tid & 63;
    const int quad = lane >> 4, l15 = lane & 15;

    // per-lane tap -> smem offset (kd*360 + kh*20 + kw), clamped for pad taps
    int offs[8];
#pragma unroll
    for (int j = 0; j < 8; ++j) {
        int tap = quad * 8 + j;
        if (tap < 27) {
            int kd = tap / 9, rem = tap - kd * 9;
            int kh = rem / 3, kw = rem - kh * 3;
            offs[j] = kd * 360 + kh * 20 + kw;
        } else offs[j] = 0;   // A is zero there; any in-range finite value ok
    }

    f32x4 acc[3][4];   // [mt][ng-local]
#pragma unroll
    for (int mt = 0; mt < 3; ++mt)
#pragma unroll
        for (int ng = 0; ng < 4; ++ng)
#pragma unroll
            for (int r = 0; r < 4; ++r) acc[mt][ng][r] = 0.0f;

#pragma unroll 1
    for (int ph = 0; ph < 2; ++ph) {
        __syncthreads();
        for (int idx = tid; idx < 5400; idx += 256) {
            int tt = idx / 1080, rem = idx % 1080;
            int kd = rem / 360, p = rem % 360;
            int row = p / 20, col = p % 20;
            int t = ph * 5 + tt;
            int h = row - 1, ww = col - 1;
            int cs = c + kd - 1;
            float v = 0.0f;
            if (cs >= 0 && cs < 256 && h >= 0 && h < 16 && ww >= 0 && ww < 16)
                v = Y[((t * 4 + b) * 256 + cs) * 256 + h * 16 + ww];
            smem[idx] = v;
        }
        __syncthreads();

#pragma unroll 1
        for (int tt = 0; tt < 5; ++tt) {
            const int t = ph * 5 + tt;
            short8 Af[3][3];   // [split][mt]
#pragma unroll
            for (int mt = 0; mt < 3; ++mt) {
                const size_t fa = ((size_t)mt * 10 + t) * 512 + lane * 8;
                Af[0][mt] = *(const short8*)(AP + fa);
                Af[1][mt] = *(const short8*)(AP + 15360 + fa);
                Af[2][mt] = *(const short8*)(AP + 30720 + fa);
            }
#pragma unroll
            for (int ng = 0; ng < 4; ++ng) {
                const int base = tt * 1080 + (wid * 4 + ng) * 20 + l15;
                short8 Bf0, Bf1, Bf2;
#pragma unroll
                for (int j = 0; j < 8; ++j) {
                    float v = smem[base + offs[j]];
                    unsigned short h1 = bf16_rne(v);
                    float r = v - bf16f(h1);
                    unsigned short h2 = bf16_rne(r);
                    float r2 = r - bf16f(h2);
                    Bf0[j] = (short)h1;
                    Bf1[j] = (short)h2;
                    Bf2[j] = (short)bf16_rne(r2);
                }
#pragma unroll
                for (int mt = 0; mt < 3; ++mt) {
                    // 6-pass order: (0,B0)(0,B1)(1,B0)(0,B2)(1,B1)(2,B0)
                    acc[mt][ng] = __builtin_amdgcn_mfma_f32_16x16x32_bf16(
                        Af[0][mt], Bf0, acc[mt][ng], 0, 0, 0);
                    acc[mt][ng] = __builtin_amdgcn_mfma_f32_16x16x32_bf16(
                        Af[0][mt], Bf1, acc[mt][ng], 0, 0, 0);
                    acc[mt][ng] = __builtin_amdgcn_mfma_f32_16x16x32_bf16(
                        Af[1][mt], Bf0, acc[mt][ng], 0, 0, 0);
                    acc[mt][ng] = __builtin_amdgcn_mfma_f32_16x16x32_bf16(
                        Af[0][mt], Bf2, acc[mt][ng], 0, 0, 0);
                    acc[mt][ng] = __builtin_amdgcn_mfma_f32_16x16x32_bf16(
                        Af[1][mt], Bf1, acc[mt][ng], 0, 0, 0);
                    acc[mt][ng] = __builtin_amdgcn_mfma_f32_16x16x32_bf16(
                        Af[2][mt], Bf0, acc[mt][ng], 0, 0, 0);
                }
            }
        }
    }

    // C -> LDS transpose: C[uc][pixel], stride 257
    __syncthreads();
#pragma unroll
    for (int mt = 0; mt < 3; ++mt)
#pragma unroll
        for (int ng = 0; ng < 4; ++ng)
#pragma unroll
            for (int r = 0; r < 4; ++r) {
                const int uc = mt * 16 + quad * 4 + r;
                const int pix = (wid * 4 + ng) * 16 + l15;
                smem[uc * 257 + pix] = acc[mt][ng][r];
            }
    __syncthreads();

    // per-pixel BN1 + inner LIF (4 residue chains), uchar spikes
    const int pix = tid;
#pragma unroll
    for (int g = 0; g < 4; ++g) {
        float mem = 0.0f;
#pragma unroll
        for (int s = 0; s < 10; ++s) {
            const int uc = 4 * s + g;
            float ga = bn1[uc], be = bn1[40 + uc], mu = bn1[80 + uc], va = bn1[120 + uc];
            float xv = (smem[uc * 257 + pix] - mu) / sqrtf(va + EPSF) * ga + be;
            mem += (xv - mem) * 0.5f;
            unsigned char spk = mem > 1.0f ? 1 : 0;
            SPK[(((size_t)b * 40 + uc) * 256 + c) * 256 + pix] = spk;
            mem = spk ? 0.0f : mem;
        }
    }
}

// ---------------------------------------------------------------------------
// TIM down grouped conv3d, merged: grid (c=256, b=4, br*10+t=30), block 256.
// ---------------------------------------------------------------------------
struct PtrArgs { float* p[3]; };
struct CPtrArgs { const float* p[3]; };

__global__ __launch_bounds__(256) void tim_down_pre5(
    const unsigned char* __restrict__ USPK, const float* __restrict__ w,
    const float* __restrict__ bn2, PtrArgs PY)
{
    __shared__ float smem[4 * 3 * 324];   // [r][cc][18*18]
    const int br = blockIdx.z / 10, t = blockIdx.z % 10;
    const unsigned char* __restrict__ SPK = USPK + (size_t)br * 10485760;
    float* __restrict__ PreY = PY.p[br];
    const int c = blockIdx.x, b = blockIdx.y;
    const int tid = threadIdx.x;
    for (int idx = tid; idx < 3888; idx += 256) {
        int r = idx / 972, rem = idx % 972;
        int cc = rem / 324, p = rem % 324;
        int hh = p / 18 - 1, ww = p % 18 - 1;
        int cs = c + cc - 1;
        float v = 0.0f;
        if (cs >= 0 && cs < 256 && hh >= 0 && hh < 16 && ww >= 0 && ww < 16)
            v = (float)SPK[(((size_t)b * 40 + 4 * t + r) * 256 + cs) * 256 + hh * 16 + ww];
        smem[idx] = v;
    }
    __syncthreads();
    const int h = tid >> 4, wq = tid & 15;
    float a = 0.0f;
#pragma unroll
    for (int r = 0; r < 4; ++r)
#pragma unroll
        for (int kd = 0; kd < 3; ++kd) {
            const float* wp = w + ((t * 4 + r) * 3 + kd) * 9;
#pragma unroll
            for (int kh = 0; kh < 3; ++kh)
#pragma unroll
                for (int kw = 0; kw < 3; ++kw)
                    a = fmaf(wp[kh * 3 + kw],
                             smem[r * 972 + kd * 324 + (h + kh) * 18 + (wq + kw)], a);
        }
    a = (a - bn2[20 + t]) / sqrtf(bn2[30 + t] + EPSF) * bn2[t] + bn2[10 + t];
    PreY[((t * 4 + b) * 256 + c) * 256 + tid] = a;
}

// Merged LIF over T (vth=1): grid (1024, 3). In-place safe (read-then-write).
__global__ __launch_bounds__(256) void lif_down3(CPtrArgs PY, PtrArgs SB)
{
    const float* __restrict__ PreY = PY.p[blockIdx.y];
    float* __restrict__ S = SB.p[blockIdx.y];
    const int idx = blockIdx.x * 256 + threadIdx.x;
    float mem = 0.0f;
    for (int t = 0; t < 10; ++t) {
        float v = PreY[t * 262144 + idx];
        mem += (v - mem) * 0.5f;
        float spk = mem > 1.0f ? 1.0f : 0.0f;
        S[t * 262144 + idx] = spk;
        mem = spk > 0.0f ? 0.0f : mem;
    }
}

// ---------------------------------------------------------------------------
// ktv[t,b,hd,j,j2] = sum_n K[..j,n] * V[..j2,n]  (exact integer dots)
// ---------------------------------------------------------------------------
__global__ __launch_bounds__(256) void ktv_k(
    const float* __restrict__ SK, const float* __restrict__ SV,
    float* __restrict__ KTV)
{
    __shared__ float ks[16 * 257], vs[16 * 257];
    const int bi = blockIdx.x;
    const int t = bi >> 6, b = (bi >> 4) & 3, hd = bi & 15;
    const int tid = threadIdx.x;
    for (int i = tid; i < 4096; i += 256) {
        int row = i >> 8, col = i & 255;
        ks[row * 257 + col] = SK[((t * 4 + b) * 256 + hd * 16 + row) * 256 + col];
        vs[row * 257 + col] = SV[((t * 4 + b) * 256 + hd * 16 + row) * 256 + col];
    }
    __syncthreads();
    const int j = tid >> 4, j2 = tid & 15;
    float a0 = 0.0f, a1 = 0.0f, a2 = 0.0f, a3 = 0.0f;
#pragma unroll 4
    for (int n = 0; n < 256; n += 4) {
        a0 = fmaf(ks[j * 257 + n + 0], vs[j2 * 257 + n + 0], a0);
        a1 = fmaf(ks[j * 257 + n + 1], vs[j2 * 257 + n + 1], a1);
        a2 = fmaf(ks[j * 257 + n + 2], vs[j2 * 257 + n + 2], a2);
        a3 = fmaf(ks[j * 257 + n + 3], vs[j2 * 257 + n + 3], a3);
    }
    KTV[((t * 4 + b) * 16 + hd) * 256 + tid] = (a0 + a1) + (a2 + a3);
}

// ---------------------------------------------------------------------------
// o = q @ ktv * 0.25 (exact) + attn_lif (vth=0.5) -> spikes written DIRECTLY
// as bf16 B-fragment pack (proj's MFMA input).
// ---------------------------------------------------------------------------
__global__ __launch_bounds__(256) void attn_k2(
    const float* __restrict__ SQ, const float* __restrict__ KTV,
    unsigned short* __restrict__ PSPK)
{
    __shared__ float kt[2560];    // [t][j*16+j2]
    __shared__ float qs[16 * 17]; // [nl][j], padded
    const int x = blockIdx.x;
    const int b = x >> 8, hd = (x >> 4) & 15, ng = x & 15;
    const int tid = threadIdx.x;
    const int j2 = tid >> 4, nl = tid & 15;
    const int n = ng * 16 + nl;
    for (int i = tid; i < 2560; i += 256) {
        int t = i >> 8;
        kt[i] = KTV[((t * 4 + b) * 16 + hd) * 256 + (i & 255)];
    }
    const int c = hd * 16 + j2;
    const int ktile = c >> 5, quad = (c >> 3) & 3, jj = c & 7;
    const int lane = quad * 16 + nl;
    float mem = 0.0f;
    for (int t = 0; t < 10; ++t) {
        __syncthreads();
        qs[nl * 17 + j2] = SQ[((t * 4 + b) * 256 + hd * 16 + j2) * 256 + n];
        __syncthreads();
        float a = 0.0f;
#pragma unroll
        for (int j = 0; j < 16; ++j)
            a = fmaf(qs[nl * 17 + j], kt[t * 256 + j * 16 + j2], a);
        a *= 0.25f;
        mem += (a - mem) * 0.5f;
        float spk = mem > 0.5f ? 1.0f : 0.0f;
        PSPK[((((size_t)(t * 4 + b) * 16 + ng) * 8 + ktile) * 512) + lane * 8 + jj] =
            spk > 0.0f ? (unsigned short)0x3F80 : (unsigned short)0;
        mem = spk > 0.0f ? 0.0f : mem;
    }
}

// LIF over T (vth=1) on P, then H = x + spikes. Per-t slice 262,144.
__global__ __launch_bounds__(256) void ssa_lif_res(
    const float* __restrict__ P, const float* __restrict__ x,
    float* __restrict__ H)
{
    const int idx = blockIdx.x * 256 + threadIdx.x;
    float mem = 0.0f;
    for (int t = 0; t < 10; ++t) {
        float v = P[t * 262144 + idx];
        mem += (v - mem) * 0.5f;
        float spk = mem > 1.0f ? 1.0f : 0.0f;
        H[t * 262144 + idx] = x[t * 262144 + idx] + spk;
        mem = spk > 0.0f ? 0.0f : mem;
    }
}

// ---------------------------------------------------------------------------
// LIF over T (vth=1) on fc1 activations + DIRECT bf16 B-fragment pack.
// ---------------------------------------------------------------------------
__global__ __launch_bounds__(256) void lif_pack(
    const float* __restrict__ A, unsigned short* __restrict__ PB)
{
    const int idx = blockIdx.x * 256 + threadIdx.x;
    const int b = idx >> 18, rem = idx & 262143;
    const int hid = rem >> 8, hw = rem & 255;
    const int ktile = hid >> 5, quad = (hid >> 3) & 3, jj = hid & 7;
    const int n16 = hw >> 4, l15 = hw & 15;
    const int lane = quad * 16 + l15;
    float mem = 0.0f;
    for (int t = 0; t < 10; ++t) {
        float v = A[t * 1048576 + idx];
        mem += (v - mem) * 0.5f;
        float spk = mem > 1.0f ? 1.0f : 0.0f;
        PB[((((size_t)(t * 4 + b) * 16 + n16) * 32 + ktile) * 512) + lane * 8 + jj] =
            spk > 0.0f ? (unsigned short)0x3F80 : (unsigned short)0;
        mem = spk > 0.0f ? 0.0f : mem;
    }
}

// out = H + lif(P) over T (vth=1). Per-t slice 262,144.
__global__ __launch_bounds__(256) void final_k(
    const float* __restrict__ P, const float* __restrict__ H,
    float* __restrict__ out)
{
    const int idx = blockIdx.x * 256 + threadIdx.x;
    float mem = 0.0f;
    for (int t = 0; t < 10; ++t) {
        float v = P[t * 262144 + idx];
        mem += (v - mem) * 0.5f;
        float spk = mem > 1.0f ? 1.0f : 0.0f;
        out[t * 262144 + idx] = H[t * 262144 + idx] + spk;
        mem = spk > 0.0f ? 0.0f : mem;
    }
}

// ---------------------------------------------------------------------------
extern "C" void kernel_launch(void* const* d_in, const int* in_sizes, int n_in,
                              void* d_out, int out_size, void* d_ws, size_t ws_size,
                              hipStream_t stream)
{
    const float* x        = (const float*)d_in[0];
    const float* q_w      = (const float*)d_in[1];
    const float* q_bn     = (const float*)d_in[2];
    const float* k_w      = (const float*)d_in[3];
    const float* k_bn     = (const float*)d_in[4];
    const float* v_w      = (const float*)d_in[5];
    const float* v_bn     = (const float*)d_in[6];
    const float* proj_w   = (const float*)d_in[7];
    const float* proj_bn  = (const float*)d_in[8];
    const float* up_w     = (const float*)d_in[9];
    const float* bn1      = (const float*)d_in[10];
    const float* down_w   = (const float*)d_in[11];
    const float* bn2      = (const float*)d_in[12];
    const float* fc1_w    = (const float*)d_in[13];
    const float* fc1_b    = (const float*)d_in[14];
    const float* fc1_bn   = (const float*)d_in[15];
    const float* fc2_w    = (const float*)d_in[16];
    const float* fc2_b    = (const float*)d_in[17];
    const float* fc2_bn   = (const float*)d_in[18];

    float* ws   = (float*)d_ws;
    float* Y    = ws;                    // 2,621,440 fl
    float* ASPK = Y + 2621440;           // 10,485,760 fl
    float* SQ   = ASPK + 10485760;       // 2,621,440 fl
    float* SK   = SQ + 2621440;          // 2,621,440 fl
    float* SV   = SK + 2621440;          // 2,621,440 fl
    float* KTV  = SV + 2621440;          // 163,840 fl (AP during tim phase, then ktv)
    unsigned short* AP = (unsigned short*)KTV;   // 46,080 halves; dead before ktv_k

    // qkv W-packs + x B-pack in ASPK (dead until tim_up6 writes spikes there)
    unsigned short* qs_s = (unsigned short*)ASPK;
    unsigned short* ks_s = qs_s + 196608;
    unsigned short* vs_s = qs_s + 393216;
    unsigned short* xp_s = qs_s + 589824;

    wpack6_k<<<8, 256, 0, stream>>>(up_w, AP);
    SplitArgs sa;
    sa.W[0] = q_w; sa.W[1] = k_w; sa.W[2] = v_w;
    sa.P[0] = qs_s; sa.P[1] = ks_s; sa.P[2] = vs_s;
    split_pack3_k<<<dim3(32, 3), 256, 0, stream>>>(sa, 256, 256);
    bpack_k<<<1280, 256, 0, stream>>>(x, xp_s, 256, 256, 40);

    MArgs qkv;
    qkv.W[0] = qs_s;  qkv.W[1] = ks_s;  qkv.W[2] = vs_s;
    qkv.Out[0] = Y; qkv.Out[1] = SK; qkv.Out[2] = SV;
    qkv.bn[0] = q_bn; qkv.bn[1] = k_bn; qkv.bn[2] = v_bn;
    mfma_gemm3<<<dim3(16, 40, 3), 256, 0, stream>>>(qkv, xp_s, nullptr, 256, 256, 256, 3);

    // merged TIM phase: uchar up-spikes (3 x 10,485,760 B) in ASPK
    unsigned char* USPK = (unsigned char*)ASPK;
    TimArgs ta; ta.Y[0] = Y; ta.Y[1] = SK; ta.Y[2] = SV;
    tim_up6<<<dim3(256, 4, 3), 256, 0, stream>>>(ta, AP, bn1, USPK);

    PtrArgs PY; PY.p[0] = Y; PY.p[1] = SK; PY.p[2] = SV;
    tim_down_pre5<<<dim3(256, 4, 30), 256, 0, stream>>>(USPK, down_w, bn2, PY);

    CPtrArgs PYc; PYc.p[0] = Y; PYc.p[1] = SK; PYc.p[2] = SV;
    PtrArgs SB; SB.p[0] = SQ; SB.p[1] = SK; SB.p[2] = SV;
    lif_down3<<<dim3(1024, 3), 256, 0, stream>>>(PYc, SB);

    ktv_k<<<640, 256, 0, stream>>>(SK, SV, KTV);
    unsigned short* PSPK = (unsigned short*)Y;
    attn_k2<<<1024, 256, 0, stream>>>(SQ, KTV, PSPK);

    // proj: packed binary B -> mfma_gemm3 nB=1
    unsigned short* pj_s = (unsigned short*)ASPK;
    split_pack_k<<<32, 256, 0, stream>>>(proj_w, pj_s, 256, 256);
    MArgs gp; gp.W[0] = gp.W[1] = gp.W[2] = pj_s;
    gp.Out[0] = gp.Out[1] = gp.Out[2] = SQ;
    gp.bn[0] = gp.bn[1] = gp.bn[2] = proj_bn;
    mfma_gemm3<<<dim3(16, 40, 1), 256, 0, stream>>>(gp, PSPK, nullptr, 256, 256, 256, 1);
    ssa_lif_res<<<1024, 256, 0, stream>>>(SQ, x, SV);       // SV <- H

    // fc1: continuous B (H) -> bpack into SQ(+SK spill); W-pack in Y
    unsigned short* f1b = (unsigned short*)SQ;
    bpack_k<<<1280, 256, 0, stream>>>(SV, f1b, 256, 256, 40);
    unsigned short* f1_s = (unsigned short*)Y;
    split_pack_k<<<128, 256, 0, stream>>>(fc1_w, f1_s, 1024, 256);
    MArgs g1; g1.W[0] = g1.W[1] = g1.W[2] = f1_s;
    g1.Out[0] = g1.Out[1] = g1.Out[2] = ASPK;
    g1.bn[0] = g1.bn[1] = g1.bn[2] = fc1_bn;
    mfma_gemm3<<<dim3(64, 40, 1), 256, 0, stream>>>(g1, f1b, fc1_b, 1024, 256, 256, 3);

    // fc2: LIF + pack fused -> PB2 in SQ+SK
    unsigned short* PB2 = (unsigned short*)SQ;
    lif_pack<<<4096, 256, 0, stream>>>(ASPK, PB2);
    unsigned short* f2_s = (unsigned short*)Y;
    split_pack_k<<<128, 256, 0, stream>>>(fc2_w, f2_s, 256, 1024);
    MArgs g2; g2.W[0] = g2.W[1] = g2.W[2] = f2_s;
    g2.Out[0] = g2.Out[1] = g2.Out[2] = ASPK;
    g2.bn[0] = g2.bn[1] = g2.bn[2] = fc2_bn;
    mfma_gemm3<<<dim3(16, 40, 1), 256, 0, stream>>>(g2, PB2, fc2_b, 256, 1024, 256, 1);
    final_k<<<1024, 256, 0, stream>>>(ASPK, SV, (float*)d_out);
}

// Round 13
// 641.048 us; speedup vs baseline: 1.7088x; 1.0498x over previous
//
#include <hip/hip_runtime.h>
#include <cstdint>
#include <cstddef>

// Problem dims (fixed)
// T=10 B=4 C=256 H=W=16 N=256 HEADS=16 d=16 HID=1024 UC=40 STEP=10 R=4
#define EPSF 1e-5f

typedef __attribute__((ext_vector_type(8))) short short8;
typedef __attribute__((ext_vector_type(4))) float f32x4;

__device__ __forceinline__ unsigned short bf16_rne(float f) {
    unsigned int u = __float_as_uint(f);
    u += 0x7FFFu + ((u >> 16) & 1u);
    return (unsigned short)(u >> 16);
}
__device__ __forceinline__ float bf16f(unsigned short h) {
    return __uint_as_float(((unsigned int)h) << 16);
}

// ---------------------------------------------------------------------------
// Split fp32 W into exact bf16x3 packed in MFMA A-fragment order (GEMMs):
// P[((p*OT + ot)*KT + kt)*512 + lane*8 + j]
// ---------------------------------------------------------------------------
__device__ __forceinline__ void split_pack_body(
    const float* __restrict__ W, unsigned short* __restrict__ P,
    int O, int K, int idx)
{
    const int OT = O >> 4, KT = K >> 5;
    const int lane = idx & 63, tile = idx >> 6;
    const int kt = tile % KT, ot = tile / KT;
    const int quad = lane >> 4, l15 = lane & 15;
    const int row = ot * 16 + l15, col = kt * 32 + quad * 8;
    const size_t base = ((size_t)ot * KT + kt) * 512 + lane * 8;
    const size_t sOff = (size_t)OT * KT * 512;
#pragma unroll
    for (int j = 0; j < 8; ++j) {
        float v = W[(size_t)row * K + col + j];
        unsigned short h1 = bf16_rne(v);
        float r = v - bf16f(h1);
        unsigned short h2 = bf16_rne(r);
        float r2 = r - bf16f(h2);
        P[base + j] = h1;
        P[sOff + base + j] = h2;
        P[2 * sOff + base + j] = bf16_rne(r2);
    }
}

__global__ __launch_bounds__(256) void split_pack_k(
    const float* __restrict__ W, unsigned short* __restrict__ P, int O, int K)
{
    int idx = blockIdx.x * 256 + threadIdx.x;
    if (idx >= (O * K) >> 3) return;
    split_pack_body(W, P, O, K, idx);
}

struct SplitArgs { const float* W[3]; unsigned short* P[3]; };
__global__ __launch_bounds__(256) void split_pack3_k(SplitArgs sa, int O, int K)
{
    int idx = blockIdx.x * 256 + threadIdx.x;
    if (idx >= (O * K) >> 3) return;
    split_pack_body(sa.W[blockIdx.y], sa.P[blockIdx.y], O, K, idx);
}

// ---------------------------------------------------------------------------
// Split fp32 activations B[s][k][n] into bf16x3 packed in MFMA B-frag order.
// ---------------------------------------------------------------------------
__global__ __launch_bounds__(256) void bpack_k(
    const float* __restrict__ B, unsigned short* __restrict__ BP,
    int K, int N, int S)
{
    const int KT = K >> 5, NT16 = N >> 4;
    int idx = blockIdx.x * 256 + threadIdx.x;
    if (idx >= S * NT16 * KT * 64) return;
    const int lane = idx & 63;
    int tile = idx >> 6;
    const int kt = tile % KT; tile /= KT;
    const int n16 = tile % NT16; const int s = tile / NT16;
    const int quad = lane >> 4, l15 = lane & 15;
    const size_t base = (size_t)idx * 8;
    const size_t sOff = (size_t)S * NT16 * KT * 512;
    const float* src = B + (size_t)s * K * N + (size_t)(kt * 32 + quad * 8) * N
                         + n16 * 16 + l15;
#pragma unroll
    for (int j = 0; j < 8; ++j) {
        float v = src[(size_t)j * N];
        unsigned short h1 = bf16_rne(v);
        float r = v - bf16f(h1);
        unsigned short h2 = bf16_rne(r);
        float r2 = r - bf16f(h2);
        BP[base + j] = h1;
        BP[sOff + base + j] = h2;
        BP[2 * sOff + base + j] = bf16_rne(r2);
    }
}

struct MArgs { const unsigned short* W[3]; float* Out[3]; const float* bn[3]; };

#define MM(AP, BQ)                                                            \
    {                                                                         \
        _Pragma("unroll") for (int mt = 0; mt < 2; ++mt)                      \
        _Pragma("unroll") for (int nt = 0; nt < 2; ++nt)                      \
            acc[mt][nt] = __builtin_amdgcn_mfma_f32_16x16x32_bf16(            \
                Af[AP][mt], Bf[BQ][nt], acc[mt][nt], 0, 0, 0);                \
    }

// ---------------------------------------------------------------------------
// MFMA GEMM v3: both operands pre-packed; no LDS/barriers in K-loop.
// ---------------------------------------------------------------------------
__global__ __launch_bounds__(256, 4) void mfma_gemm3(
    MArgs a, const unsigned short* __restrict__ BP,
    const float* __restrict__ bias, int O, int K, int N, int nB)
{
    const unsigned short* __restrict__ W = a.W[blockIdx.z];
    float* __restrict__ Out = a.Out[blockIdx.z];
    const float* __restrict__ bnp = a.bn[blockIdx.z];
    const int OT = O >> 4, KT = K >> 5, NT16 = N >> 4;
    const size_t sA = (size_t)OT * KT * 512;
    const size_t sB = (size_t)gridDim.y * NT16 * KT * 512;

    const int slice  = blockIdx.y;
    const int tilesn = N >> 6;
    const int to = (blockIdx.x / tilesn) << 6;
    const int tn = (blockIdx.x % tilesn) << 6;
    const int tid = threadIdx.x;
    const int wid = tid >> 6, lane = tid & 63;
    const int quad = lane >> 4, l15 = lane & 15;
    const int wm = (wid >> 1) << 5, wn = (wid & 1) << 5;
    const int oti0 = (to + wm) >> 4;
    const int n160 = (tn + wn) >> 4;

    f32x4 acc[2][2];
#pragma unroll
    for (int mt = 0; mt < 2; ++mt)
#pragma unroll
        for (int nt = 0; nt < 2; ++nt)
#pragma unroll
            for (int r = 0; r < 4; ++r) acc[mt][nt][r] = 0.0f;

    for (int kt = 0; kt < KT; ++kt) {
        short8 Af[3][2], Bf[3][2];
#pragma unroll
        for (int mt = 0; mt < 2; ++mt) {
            const size_t fa = ((size_t)(oti0 + mt) * KT + kt) * 512 + lane * 8;
            Af[0][mt] = *(const short8*)(W + fa);
            Af[1][mt] = *(const short8*)(W + sA + fa);
            Af[2][mt] = *(const short8*)(W + 2 * sA + fa);
        }
#pragma unroll
        for (int nt = 0; nt < 2; ++nt) {
            const size_t fb =
                (((size_t)slice * NT16 + n160 + nt) * KT + kt) * 512 + lane * 8;
            Bf[0][nt] = *(const short8*)(BP + fb);
            if (nB == 3) {
                Bf[1][nt] = *(const short8*)(BP + sB + fb);
                Bf[2][nt] = *(const short8*)(BP + 2 * sB + fb);
            }
        }
        if (nB == 3) {
            MM(0, 0) MM(0, 1) MM(1, 0) MM(0, 2) MM(1, 1) MM(2, 0)
        } else {
            MM(0, 0) MM(1, 0) MM(2, 0)
        }
    }

    float* Op = Out + (size_t)slice * O * N;
#pragma unroll
    for (int mt = 0; mt < 2; ++mt) {
#pragma unroll
        for (int r = 0; r < 4; ++r) {
            const int o = to + wm + (mt << 4) + (quad << 2) + r;
            float g = bnp[o], bb = bnp[O + o], m = bnp[2 * O + o], vv = bnp[3 * O + o];
            float sq = sqrtf(vv + EPSF);
            float bs = bias ? bias[o] : 0.0f;
#pragma unroll
            for (int nt = 0; nt < 2; ++nt) {
                const int n = tn + wn + (nt << 4) + l15;
                float val = acc[mt][nt][r] + bs;
                Op[(size_t)o * N + n] = (val - m) / sq * g + bb;
            }
        }
    }
}

// ---------------------------------------------------------------------------
// tim_up weight pack for MFMA conv: A[m=uc(pad 48)][k=t*32+tap(pad 27->32)]
// AP[((p*3+mt)*10 + t)*512 + lane*8 + j]; zero for uc>=40 or tap>=27.
// ---------------------------------------------------------------------------
__global__ __launch_bounds__(256) void wpack6_k(
    const float* __restrict__ up_w, unsigned short* __restrict__ AP)
{
    int idx = blockIdx.x * 256 + threadIdx.x;
    if (idx >= 1920) return;
    const int lane = idx & 63, rest = idx >> 6;
    const int t = rest % 10, mt = rest / 10;
    const int quad = lane >> 4, l15 = lane & 15;
    const int uc = mt * 16 + l15;
    const size_t base = ((size_t)mt * 10 + t) * 512 + lane * 8;
#pragma unroll
    for (int j = 0; j < 8; ++j) {
        int tap = quad * 8 + j;
        float v = 0.0f;
        if (uc < 40 && tap < 27) v = up_w[uc * 270 + t * 27 + tap];
        unsigned short h1 = bf16_rne(v);
        float r = v - bf16f(h1);
        unsigned short h2 = bf16_rne(r);
        float r2 = r - bf16f(h2);
        AP[base + j] = h1;
        AP[15360 + base + j] = h2;
        AP[30720 + base + j] = bf16_rne(r2);
    }
}

// ---------------------------------------------------------------------------
// TIM up conv3d as MFMA + BN1 + inner LIF, v7.
// v6 lesson: per-tap in-register bf16x3 split = 27x redundant (~4800 VALU/
// thread, VALUBusy 71%). v7 splits each Y value ONCE during LDS staging and
// stores three u16 bf16 planes; fragment build is pure ds_read_u16 + pack.
// Split values and 6-pass MFMA order bit-identical to v6.
// Grid (c=256, b=4, br=3), block 256 = 4 waves; M=48(uc pad), K=10x32 taps,
// N=256 pixels. C -> LDS transpose (stride 257) -> per-pixel BN1+LIF ->
// uchar spikes (layout unchanged).
// ---------------------------------------------------------------------------
struct TimArgs { const float* Y[3]; };

__global__ __launch_bounds__(256, 2) void tim_up7(
    TimArgs ta, const unsigned short* __restrict__ AP,
    const float* __restrict__ bn1, unsigned char* __restrict__ USPK)
{
    // union: bf16x3 staging planes (3 x 5400 u16 = 32,400 B) | C 48x257 f32
    __shared__ float smem[12336];
    unsigned short* smem16 = (unsigned short*)smem;
    const float* __restrict__ Y = ta.Y[blockIdx.z];
    unsigned char* __restrict__ SPK = USPK + (size_t)blockIdx.z * 10485760;
    const int c = blockIdx.x, b = blockIdx.y;
    const int tid = threadIdx.x;
    const int wid = tid >> 6, lane = tid & 63;
    const int quad = lane >> 4, l15 = lane & 15;

    // per-lane tap -> smem offset (kd*360 + kh*20 + kw), 0 for pad taps
    int offs[8];
#pragma unroll
    for (int j = 0; j < 8; ++j) {
        int tap = quad * 8 + j;
        if (tap < 27) {
            int kd = tap / 9, rem = tap - kd * 9;
            int kh = rem / 3, kw = rem - kh * 3;
            offs[j] = kd * 360 + kh * 20 + kw;
        } else offs[j] = 0;   // A is zero there; any staged value is fine
    }

    f32x4 acc[3][4];   // [mt][ng-local]
#pragma unroll
    for (int mt = 0; mt < 3; ++mt)
#pragma unroll
        for (int ng = 0; ng < 4; ++ng)
#pragma unroll
            for (int r = 0; r < 4; ++r) acc[mt][ng][r] = 0.0f;

#pragma unroll 1
    for (int ph = 0; ph < 2; ++ph) {
        __syncthreads();
        for (int idx = tid; idx < 5400; idx += 256) {
            int tt = idx / 1080, rem = idx % 1080;
            int kd = rem / 360, p = rem % 360;
            int row = p / 20, col = p % 20;
            int t = ph * 5 + tt;
            int h = row - 1, ww = col - 1;
            int cs = c + kd - 1;
            float v = 0.0f;
            if (cs >= 0 && cs < 256 && h >= 0 && h < 16 && ww >= 0 && ww < 16)
                v = Y[((t * 4 + b) * 256 + cs) * 256 + h * 16 + ww];
            unsigned short h1 = bf16_rne(v);
            float r = v - bf16f(h1);
            unsigned short h2 = bf16_rne(r);
            float r2 = r - bf16f(h2);
            smem16[idx] = h1;
            smem16[5400 + idx] = h2;
            smem16[10800 + idx] = bf16_rne(r2);
        }
        __syncthreads();

#pragma unroll 1
        for (int tt = 0; tt < 5; ++tt) {
            const int t = ph * 5 + tt;
            short8 Af[3][3];   // [split][mt]
#pragma unroll
            for (int mt = 0; mt < 3; ++mt) {
                const size_t fa = ((size_t)mt * 10 + t) * 512 + lane * 8;
                Af[0][mt] = *(const short8*)(AP + fa);
                Af[1][mt] = *(const short8*)(AP + 15360 + fa);
                Af[2][mt] = *(const short8*)(AP + 30720 + fa);
            }
#pragma unroll
            for (int ng = 0; ng < 4; ++ng) {
                const int base = tt * 1080 + (wid * 4 + ng) * 20 + l15;
                short8 Bf0, Bf1, Bf2;
#pragma unroll
                for (int j = 0; j < 8; ++j) {
                    Bf0[j] = (short)smem16[base + offs[j]];
                    Bf1[j] = (short)smem16[5400 + base + offs[j]];
                    Bf2[j] = (short)smem16[10800 + base + offs[j]];
                }
#pragma unroll
                for (int mt = 0; mt < 3; ++mt) {
                    // 6-pass order: (0,B0)(0,B1)(1,B0)(0,B2)(1,B1)(2,B0)
                    acc[mt][ng] = __builtin_amdgcn_mfma_f32_16x16x32_bf16(
                        Af[0][mt], Bf0, acc[mt][ng], 0, 0, 0);
                    acc[mt][ng] = __builtin_amdgcn_mfma_f32_16x16x32_bf16(
                        Af[0][mt], Bf1, acc[mt][ng], 0, 0, 0);
                    acc[mt][ng] = __builtin_amdgcn_mfma_f32_16x16x32_bf16(
                        Af[1][mt], Bf0, acc[mt][ng], 0, 0, 0);
                    acc[mt][ng] = __builtin_amdgcn_mfma_f32_16x16x32_bf16(
                        Af[0][mt], Bf2, acc[mt][ng], 0, 0, 0);
                    acc[mt][ng] = __builtin_amdgcn_mfma_f32_16x16x32_bf16(
                        Af[1][mt], Bf1, acc[mt][ng], 0, 0, 0);
                    acc[mt][ng] = __builtin_amdgcn_mfma_f32_16x16x32_bf16(
                        Af[2][mt], Bf0, acc[mt][ng], 0, 0, 0);
                }
            }
        }
    }

    // C -> LDS transpose: C[uc][pixel], stride 257
    __syncthreads();
#pragma unroll
    for (int mt = 0; mt < 3; ++mt)
#pragma unroll
        for (int ng = 0; ng < 4; ++ng)
#pragma unroll
            for (int r = 0; r < 4; ++r) {
                const int uc = mt * 16 + quad * 4 + r;
                const int pix = (wid * 4 + ng) * 16 + l15;
                smem[uc * 257 + pix] = acc[mt][ng][r];
            }
    __syncthreads();

    // per-pixel BN1 + inner LIF (4 residue chains), uchar spikes
    const int pix = tid;
#pragma unroll
    for (int g = 0; g < 4; ++g) {
        float mem = 0.0f;
#pragma unroll
        for (int s = 0; s < 10; ++s) {
            const int uc = 4 * s + g;
            float ga = bn1[uc], be = bn1[40 + uc], mu = bn1[80 + uc], va = bn1[120 + uc];
            float xv = (smem[uc * 257 + pix] - mu) / sqrtf(va + EPSF) * ga + be;
            mem += (xv - mem) * 0.5f;
            unsigned char spk = mem > 1.0f ? 1 : 0;
            SPK[(((size_t)b * 40 + uc) * 256 + c) * 256 + pix] = spk;
            mem = spk ? 0.0f : mem;
        }
    }
}

// ---------------------------------------------------------------------------
// TIM down grouped conv3d, merged: grid (c=256, b=4, br*10+t=30), block 256.
// ---------------------------------------------------------------------------
struct PtrArgs { float* p[3]; };
struct CPtrArgs { const float* p[3]; };

__global__ __launch_bounds__(256) void tim_down_pre5(
    const unsigned char* __restrict__ USPK, const float* __restrict__ w,
    const float* __restrict__ bn2, PtrArgs PY)
{
    __shared__ float smem[4 * 3 * 324];   // [r][cc][18*18]
    const int br = blockIdx.z / 10, t = blockIdx.z % 10;
    const unsigned char* __restrict__ SPK = USPK + (size_t)br * 10485760;
    float* __restrict__ PreY = PY.p[br];
    const int c = blockIdx.x, b = blockIdx.y;
    const int tid = threadIdx.x;
    for (int idx = tid; idx < 3888; idx += 256) {
        int r = idx / 972, rem = idx % 972;
        int cc = rem / 324, p = rem % 324;
        int hh = p / 18 - 1, ww = p % 18 - 1;
        int cs = c + cc - 1;
        float v = 0.0f;
        if (cs >= 0 && cs < 256 && hh >= 0 && hh < 16 && ww >= 0 && ww < 16)
            v = (float)SPK[(((size_t)b * 40 + 4 * t + r) * 256 + cs) * 256 + hh * 16 + ww];
        smem[idx] = v;
    }
    __syncthreads();
    const int h = tid >> 4, wq = tid & 15;
    float a = 0.0f;
#pragma unroll
    for (int r = 0; r < 4; ++r)
#pragma unroll
        for (int kd = 0; kd < 3; ++kd) {
            const float* wp = w + ((t * 4 + r) * 3 + kd) * 9;
#pragma unroll
            for (int kh = 0; kh < 3; ++kh)
#pragma unroll
                for (int kw = 0; kw < 3; ++kw)
                    a = fmaf(wp[kh * 3 + kw],
                             smem[r * 972 + kd * 324 + (h + kh) * 18 + (wq + kw)], a);
        }
    a = (a - bn2[20 + t]) / sqrtf(bn2[30 + t] + EPSF) * bn2[t] + bn2[10 + t];
    PreY[((t * 4 + b) * 256 + c) * 256 + tid] = a;
}

// Merged LIF over T (vth=1): grid (1024, 3). In-place safe (read-then-write).
__global__ __launch_bounds__(256) void lif_down3(CPtrArgs PY, PtrArgs SB)
{
    const float* __restrict__ PreY = PY.p[blockIdx.y];
    float* __restrict__ S = SB.p[blockIdx.y];
    const int idx = blockIdx.x * 256 + threadIdx.x;
    float mem = 0.0f;
    for (int t = 0; t < 10; ++t) {
        float v = PreY[t * 262144 + idx];
        mem += (v - mem) * 0.5f;
        float spk = mem > 1.0f ? 1.0f : 0.0f;
        S[t * 262144 + idx] = spk;
        mem = spk > 0.0f ? 0.0f : mem;
    }
}

// ---------------------------------------------------------------------------
// ktv[t,b,hd,j,j2] = sum_n K[..j,n] * V[..j2,n]  (exact integer dots)
// ---------------------------------------------------------------------------
__global__ __launch_bounds__(256) void ktv_k(
    const float* __restrict__ SK, const float* __restrict__ SV,
    float* __restrict__ KTV)
{
    __shared__ float ks[16 * 257], vs[16 * 257];
    const int bi = blockIdx.x;
    const int t = bi >> 6, b = (bi >> 4) & 3, hd = bi & 15;
    const int tid = threadIdx.x;
    for (int i = tid; i < 4096; i += 256) {
        int row = i >> 8, col = i & 255;
        ks[row * 257 + col] = SK[((t * 4 + b) * 256 + hd * 16 + row) * 256 + col];
        vs[row * 257 + col] = SV[((t * 4 + b) * 256 + hd * 16 + row) * 256 + col];
    }
    __syncthreads();
    const int j = tid >> 4, j2 = tid & 15;
    float a0 = 0.0f, a1 = 0.0f, a2 = 0.0f, a3 = 0.0f;
#pragma unroll 4
    for (int n = 0; n < 256; n += 4) {
        a0 = fmaf(ks[j * 257 + n + 0], vs[j2 * 257 + n + 0], a0);
        a1 = fmaf(ks[j * 257 + n + 1], vs[j2 * 257 + n + 1], a1);
        a2 = fmaf(ks[j * 257 + n + 2], vs[j2 * 257 + n + 2], a2);
        a3 = fmaf(ks[j * 257 + n + 3], vs[j2 * 257 + n + 3], a3);
    }
    KTV[((t * 4 + b) * 16 + hd) * 256 + tid] = (a0 + a1) + (a2 + a3);
}

// ---------------------------------------------------------------------------
// o = q @ ktv * 0.25 (exact) + attn_lif (vth=0.5) -> spikes written DIRECTLY
// as bf16 B-fragment pack (proj's MFMA input).
// ---------------------------------------------------------------------------
__global__ __launch_bounds__(256) void attn_k2(
    const float* __restrict__ SQ, const float* __restrict__ KTV,
    unsigned short* __restrict__ PSPK)
{
    __shared__ float kt[2560];    // [t][j*16+j2]
    __shared__ float qs[16 * 17]; // [nl][j], padded
    const int x = blockIdx.x;
    const int b = x >> 8, hd = (x >> 4) & 15, ng = x & 15;
    const int tid = threadIdx.x;
    const int j2 = tid >> 4, nl = tid & 15;
    const int n = ng * 16 + nl;
    for (int i = tid; i < 2560; i += 256) {
        int t = i >> 8;
        kt[i] = KTV[((t * 4 + b) * 16 + hd) * 256 + (i & 255)];
    }
    const int c = hd * 16 + j2;
    const int ktile = c >> 5, quad = (c >> 3) & 3, jj = c & 7;
    const int lane = quad * 16 + nl;
    float mem = 0.0f;
    for (int t = 0; t < 10; ++t) {
        __syncthreads();
        qs[nl * 17 + j2] = SQ[((t * 4 + b) * 256 + hd * 16 + j2) * 256 + n];
        __syncthreads();
        float a = 0.0f;
#pragma unroll
        for (int j = 0; j < 16; ++j)
            a = fmaf(qs[nl * 17 + j], kt[t * 256 + j * 16 + j2], a);
        a *= 0.25f;
        mem += (a - mem) * 0.5f;
        float spk = mem > 0.5f ? 1.0f : 0.0f;
        PSPK[((((size_t)(t * 4 + b) * 16 + ng) * 8 + ktile) * 512) + lane * 8 + jj] =
            spk > 0.0f ? (unsigned short)0x3F80 : (unsigned short)0;
        mem = spk > 0.0f ? 0.0f : mem;
    }
}

// LIF over T (vth=1) on P, then H = x + spikes. Per-t slice 262,144.
__global__ __launch_bounds__(256) void ssa_lif_res(
    const float* __restrict__ P, const float* __restrict__ x,
    float* __restrict__ H)
{
    const int idx = blockIdx.x * 256 + threadIdx.x;
    float mem = 0.0f;
    for (int t = 0; t < 10; ++t) {
        float v = P[t * 262144 + idx];
        mem += (v - mem) * 0.5f;
        float spk = mem > 1.0f ? 1.0f : 0.0f;
        H[t * 262144 + idx] = x[t * 262144 + idx] + spk;
        mem = spk > 0.0f ? 0.0f : mem;
    }
}

// ---------------------------------------------------------------------------
// LIF over T (vth=1) on fc1 activations + DIRECT bf16 B-fragment pack.
// ---------------------------------------------------------------------------
__global__ __launch_bounds__(256) void lif_pack(
    const float* __restrict__ A, unsigned short* __restrict__ PB)
{
    const int idx = blockIdx.x * 256 + threadIdx.x;
    const int b = idx >> 18, rem = idx & 262143;
    const int hid = rem >> 8, hw = rem & 255;
    const int ktile = hid >> 5, quad = (hid >> 3) & 3, jj = hid & 7;
    const int n16 = hw >> 4, l15 = hw & 15;
    const int lane = quad * 16 + l15;
    float mem = 0.0f;
    for (int t = 0; t < 10; ++t) {
        float v = A[t * 1048576 + idx];
        mem += (v - mem) * 0.5f;
        float spk = mem > 1.0f ? 1.0f : 0.0f;
        PB[((((size_t)(t * 4 + b) * 16 + n16) * 32 + ktile) * 512) + lane * 8 + jj] =
            spk > 0.0f ? (unsigned short)0x3F80 : (unsigned short)0;
        mem = spk > 0.0f ? 0.0f : mem;
    }
}

// out = H + lif(P) over T (vth=1). Per-t slice 262,144.
__global__ __launch_bounds__(256) void final_k(
    const float* __restrict__ P, const float* __restrict__ H,
    float* __restrict__ out)
{
    const int idx = blockIdx.x * 256 + threadIdx.x;
    float mem = 0.0f;
    for (int t = 0; t < 10; ++t) {
        float v = P[t * 262144 + idx];
        mem += (v - mem) * 0.5f;
        float spk = mem > 1.0f ? 1.0f : 0.0f;
        out[t * 262144 + idx] = H[t * 262144 + idx] + spk;
        mem = spk > 0.0f ? 0.0f : mem;
    }
}

// ---------------------------------------------------------------------------
extern "C" void kernel_launch(void* const* d_in, const int* in_sizes, int n_in,
                              void* d_out, int out_size, void* d_ws, size_t ws_size,
                              hipStream_t stream)
{
    const float* x        = (const float*)d_in[0];
    const float* q_w      = (const float*)d_in[1];
    const float* q_bn     = (const float*)d_in[2];
    const float* k_w      = (const float*)d_in[3];
    const float* k_bn     = (const float*)d_in[4];
    const float* v_w      = (const float*)d_in[5];
    const float* v_bn     = (const float*)d_in[6];
    const float* proj_w   = (const float*)d_in[7];
    const float* proj_bn  = (const float*)d_in[8];
    const float* up_w     = (const float*)d_in[9];
    const float* bn1      = (const float*)d_in[10];
    const float* down_w   = (const float*)d_in[11];
    const float* bn2      = (const float*)d_in[12];
    const float* fc1_w    = (const float*)d_in[13];
    const float* fc1_b    = (const float*)d_in[14];
    const float* fc1_bn   = (const float*)d_in[15];
    const float* fc2_w    = (const float*)d_in[16];
    const float* fc2_b    = (const float*)d_in[17];
    const float* fc2_bn   = (const float*)d_in[18];

    float* ws   = (float*)d_ws;
    float* Y    = ws;                    // 2,621,440 fl
    float* ASPK = Y + 2621440;           // 10,485,760 fl
    float* SQ   = ASPK + 10485760;       // 2,621,440 fl
    float* SK   = SQ + 2621440;          // 2,621,440 fl
    float* SV   = SK + 2621440;          // 2,621,440 fl
    float* KTV  = SV + 2621440;          // 163,840 fl (AP during tim phase, then ktv)
    unsigned short* AP = (unsigned short*)KTV;   // 46,080 halves; dead before ktv_k

    // qkv W-packs + x B-pack in ASPK (dead until tim_up7 writes spikes there)
    unsigned short* qs_s = (unsigned short*)ASPK;
    unsigned short* ks_s = qs_s + 196608;
    unsigned short* vs_s = qs_s + 393216;
    unsigned short* xp_s = qs_s + 589824;

    wpack6_k<<<8, 256, 0, stream>>>(up_w, AP);
    SplitArgs sa;
    sa.W[0] = q_w; sa.W[1] = k_w; sa.W[2] = v_w;
    sa.P[0] = qs_s; sa.P[1] = ks_s; sa.P[2] = vs_s;
    split_pack3_k<<<dim3(32, 3), 256, 0, stream>>>(sa, 256, 256);
    bpack_k<<<1280, 256, 0, stream>>>(x, xp_s, 256, 256, 40);

    MArgs qkv;
    qkv.W[0] = qs_s;  qkv.W[1] = ks_s;  qkv.W[2] = vs_s;
    qkv.Out[0] = Y; qkv.Out[1] = SK; qkv.Out[2] = SV;
    qkv.bn[0] = q_bn; qkv.bn[1] = k_bn; qkv.bn[2] = v_bn;
    mfma_gemm3<<<dim3(16, 40, 3), 256, 0, stream>>>(qkv, xp_s, nullptr, 256, 256, 256, 3);

    // merged TIM phase: uchar up-spikes (3 x 10,485,760 B) in ASPK
    unsigned char* USPK = (unsigned char*)ASPK;
    TimArgs ta; ta.Y[0] = Y; ta.Y[1] = SK; ta.Y[2] = SV;
    tim_up7<<<dim3(256, 4, 3), 256, 0, stream>>>(ta, AP, bn1, USPK);

    PtrArgs PY; PY.p[0] = Y; PY.p[1] = SK; PY.p[2] = SV;
    tim_down_pre5<<<dim3(256, 4, 30), 256, 0, stream>>>(USPK, down_w, bn2, PY);

    CPtrArgs PYc; PYc.p[0] = Y; PYc.p[1] = SK; PYc.p[2] = SV;
    PtrArgs SB; SB.p[0] = SQ; SB.p[1] = SK; SB.p[2] = SV;
    lif_down3<<<dim3(1024, 3), 256, 0, stream>>>(PYc, SB);

    ktv_k<<<640, 256, 0, stream>>>(SK, SV, KTV);
    unsigned short* PSPK = (unsigned short*)Y;
    attn_k2<<<1024, 256, 0, stream>>>(SQ, KTV, PSPK);

    // proj: packed binary B -> mfma_gemm3 nB=1
    unsigned short* pj_s = (unsigned short*)ASPK;
    split_pack_k<<<32, 256, 0, stream>>>(proj_w, pj_s, 256, 256);
    MArgs gp; gp.W[0] = gp.W[1] = gp.W[2] = pj_s;
    gp.Out[0] = gp.Out[1] = gp.Out[2] = SQ;
    gp.bn[0] = gp.bn[1] = gp.bn[2] = proj_bn;
    mfma_gemm3<<<dim3(16, 40, 1), 256, 0, stream>>>(gp, PSPK, nullptr, 256, 256, 256, 1);
    ssa_lif_res<<<1024, 256, 0, stream>>>(SQ, x, SV);       // SV <- H

    // fc1: continuous B (H) -> bpack into SQ(+SK spill); W-pack in Y
    unsigned short* f1b = (unsigned short*)SQ;
    bpack_k<<<1280, 256, 0, stream>>>(SV, f1b, 256, 256, 40);
    unsigned short* f1_s = (unsigned short*)Y;
    split_pack_k<<<128, 256, 0, stream>>>(fc1_w, f1_s, 1024, 256);
    MArgs g1; g1.W[0] = g1.W[1] = g1.W[2] = f1_s;
    g1.Out[0] = g1.Out[1] = g1.Out[2] = ASPK;
    g1.bn[0] = g1.bn[1] = g1.bn[2] = fc1_bn;
    mfma_gemm3<<<dim3(64, 40, 1), 256, 0, stream>>>(g1, f1b, fc1_b, 1024, 256, 256, 3);

    // fc2: LIF + pack fused -> PB2 in SQ+SK
    unsigned short* PB2 = (unsigned short*)SQ;
    lif_pack<<<4096, 256, 0, stream>>>(ASPK, PB2);
    unsigned short* f2_s = (unsigned short*)Y;
    split_pack_k<<<128, 256, 0, stream>>>(fc2_w, f2_s, 256, 1024);
    MArgs g2; g2.W[0] = g2.W[1] = g2.W[2] = f2_s;
    g2.Out[0] = g2.Out[1] = g2.Out[2] = ASPK;
    g2.bn[0] = g2.bn[1] = g2.bn[2] = fc2_bn;
    mfma_gemm3<<<dim3(16, 40, 1), 256, 0, stream>>>(g2, PB2, fc2_b, 256, 1024, 256, 1);
    final_k<<<1024, 256, 0, stream>>>(ASPK, SV, (float*)d_out);
}